// Round 8
// baseline (659.083 us; speedup 1.0000x reference)
//
#include <hip/hip_runtime.h>

// QMN B=32,T=60,D=128. Round 8.
// r7: meas stall-bound (cold global Si frags, Sr staged 2x, 8 waves/CU);
// conj kernels staging-bound at 2 blk/CU (B-matrix needlessly in LDS).
// Changes:
//  - conjL1/conjmid: B (GT/M, L2-hot) read as global 16B frags; LDS = data
//    only (34.8KB) -> 4 blk/CU (16 waves), 256 thr, 4x4 tiles.
//  - k_meas: one block per tb (1920 x 512thr): Sr staged once, Si prefetched
//    to regs -> dumped into Sr's buffer when dead, W via global L2 frags.
//    3 phases (Sr.Wr^T, Sr.Wi^T, Si.Wi^T) + diag-tile extraction, signs
//    identical to r7 (cross coeff -2).

#define DB 32
#define DT 60
#define DD 128
#define BT (DB*DT)
#define SP 136
#define BSTR 36

typedef unsigned short ushort_t;
typedef __attribute__((ext_vector_type(8))) __bf16 bf16x8;
typedef __attribute__((ext_vector_type(4))) float  float4v;

__device__ __forceinline__ float bf2f(ushort_t u){
  union { unsigned int i; float f; } x; x.i = ((unsigned int)u) << 16; return x.f;
}
__device__ __forceinline__ ushort_t f2bf(float f){
  union { float f; unsigned int i; } x; x.f = f;
  unsigned int lsb = (x.i >> 16) & 1u;
  return (ushort_t)((x.i + 0x7FFFu + lsb) >> 16);
}
__device__ __forceinline__ unsigned int f2bfpk(float a, float b){
#if defined(__gfx950__) && __has_builtin(__builtin_amdgcn_cvt_pk_bf16_f32)
  auto v = __builtin_amdgcn_cvt_pk_bf16_f32(a, b);
  unsigned int r; __builtin_memcpy(&r, &v, 4); return r;
#else
  return (unsigned int)f2bf(a) | ((unsigned int)f2bf(b) << 16);
#endif
}
__device__ __forceinline__ void split2(float v, ushort_t& h, ushort_t& l){
  h = f2bf(v); l = f2bf(v - bf2f(h));
}

// D[m][n] = sum_k A[m][k]*B[n][k]; A,B in LDS (stride SP). hi/lo optional.
template<int RT, int CT, bool ALO, bool BLO>
__device__ __forceinline__ void gemm_t(const ushort_t* Ah, const ushort_t* Al,
                                       const ushort_t* Bh, const ushort_t* Bl,
                                       float4v* acc, int row0, int col0, int gma, int q)
{
  for (int ks = 0; ks < 4; ks++){
    int ko = ks*32 + q*8;
    bf16x8 aF[RT], aL[RT], bF[CT], bL[CT];
    #pragma unroll
    for (int R = 0; R < RT; R++){
      int row = row0 + 16*R + gma;
      aF[R] = *(const bf16x8*)&Ah[row*SP + ko];
      if (ALO) aL[R] = *(const bf16x8*)&Al[row*SP + ko];
    }
    #pragma unroll
    for (int C = 0; C < CT; C++){
      int row = col0 + 16*C + gma;
      bF[C] = *(const bf16x8*)&Bh[row*SP + ko];
      if (BLO) bL[C] = *(const bf16x8*)&Bl[row*SP + ko];
    }
    #pragma unroll
    for (int R = 0; R < RT; R++)
      #pragma unroll
      for (int C = 0; C < CT; C++){
        float4v c = acc[R*CT+C];
        c = __builtin_amdgcn_mfma_f32_16x16x32_bf16(aF[R], bF[C], c, 0, 0, 0);
        if (BLO) c = __builtin_amdgcn_mfma_f32_16x16x32_bf16(aF[R], bL[C], c, 0, 0, 0);
        if (ALO) c = __builtin_amdgcn_mfma_f32_16x16x32_bf16(aL[R], bF[C], c, 0, 0, 0);
        acc[R*CT+C] = c;
      }
  }
}

// D[m][n] = sum_k A[m][k]*B[n][k]; A in LDS (SP), B in GLOBAL (stride 128).
template<int RT, int CT>
__device__ __forceinline__ void gemm_bg(const ushort_t* A, const ushort_t* Bg,
                                        float4v* acc, int row0, int col0, int gma, int q)
{
  for (int ks = 0; ks < 4; ks++){
    int ko = ks*32 + q*8;
    bf16x8 aF[RT], bF[CT];
    #pragma unroll
    for (int C = 0; C < CT; C++){
      int row = col0 + 16*C + gma;
      bF[C] = *(const bf16x8*)&Bg[(size_t)row*128 + ko];
    }
    #pragma unroll
    for (int R = 0; R < RT; R++){
      int row = row0 + 16*R + gma;
      aF[R] = *(const bf16x8*)&A[row*SP + ko];
    }
    #pragma unroll
    for (int R = 0; R < RT; R++)
      #pragma unroll
      for (int C = 0; C < CT; C++)
        acc[R*CT+C] = __builtin_amdgcn_mfma_f32_16x16x32_bf16(aF[R], bF[C], acc[R*CT+C], 0, 0, 0);
  }
}

// transposed store computed(m,n) -> dst[n*stride + m] (single bf16)
template<int RT, int CT>
__device__ __forceinline__ void emit_t(const float4v* acc, ushort_t* dst, int stride,
                                       int row0, int col0, int gma, int q){
  #pragma unroll
  for (int R = 0; R < RT; R++)
    #pragma unroll
    for (int C = 0; C < CT; C++){
      int c = col0 + 16*C + gma, r0 = row0 + 16*R + 4*q;
      uint2 o;
      o.x = f2bfpk(acc[R*CT+C][0], acc[R*CT+C][1]);
      o.y = f2bfpk(acc[R*CT+C][2], acc[R*CT+C][3]);
      *(uint2*)&dst[(size_t)c*stride + r0] = o;
    }
}
__device__ __forceinline__ void emit_split44(const float4v* acc, ushort_t* dh, ushort_t* dl, int stride,
                                             int row0, int col0, int gma, int q){
  #pragma unroll
  for (int R = 0; R < 4; R++)
    #pragma unroll
    for (int C = 0; C < 4; C++){
      int c = col0 + 16*C + gma, r0 = row0 + 16*R + 4*q;
      ushort4 hh, ll;
      split2(acc[R*4+C][0], hh.x, ll.x); split2(acc[R*4+C][1], hh.y, ll.y);
      split2(acc[R*4+C][2], hh.z, ll.z); split2(acc[R*4+C][3], hh.w, ll.w);
      *(ushort4*)&dh[(size_t)c*stride + r0] = hh;
      *(ushort4*)&dl[(size_t)c*stride + r0] = ll;
    }
}
__device__ __forceinline__ void emit_plain_lds44(const float4v* acc, ushort_t* dh, ushort_t* dl,
                                                 int row0, int col0, int gma, int q){
  #pragma unroll
  for (int R = 0; R < 4; R++)
    #pragma unroll
    for (int C = 0; C < 4; C++){
      int c = col0 + 16*C + gma, r0 = row0 + 16*R + 4*q;
      #pragma unroll
      for (int j = 0; j < 4; j++){
        ushort_t h, l; split2(acc[R*4+C][j], h, l);
        dh[(size_t)(r0+j)*SP + c] = h;
        dl[(size_t)(r0+j)*SP + c] = l;
      }
    }
}
template<int NT>
__device__ __forceinline__ void lds_load_mat(ushort_t* dst, const ushort_t* src, int tid){
  for (int i = tid*4; i < 16384; i += NT*4){
    int r = i >> 7, k = i & 127;
    *(ushort4*)&dst[r*SP + k] = *(const ushort4*)&src[i];
  }
}
template<int NT>
__device__ __forceinline__ void lds_store_mat(ushort_t* dst, const ushort_t* src, int tid){
  for (int i = tid*4; i < 16384; i += NT*4){
    int r = i >> 7, k = i & 127;
    *(ushort4*)&dst[i] = *(const ushort4*)&src[r*SP + k];
  }
}

// ---- small: prepU | normv | initG ----
__global__ void k_small(const float* Ux, const float* Uh, const float* kr, const float* ki,
                        ushort_t* UxTh, ushort_t* UxTl, float* Vr, float* Vi,
                        ushort_t* PpH, ushort_t* PpL, ushort_t* PTh, ushort_t* PTl){
  int blk = blockIdx.x, d = threadIdx.x;
  if (blk < 128){
    int i = blk;
    float v = Ux[i*DD + d];
    ushort_t h, l; split2(v, h, l);
    UxTh[d*DD + i] = h; UxTl[d*DD + i] = l;
  } else if (blk < 256){
    __shared__ float red[DD];
    int k = blk - 128;
    float r = kr[k*DD+d], im = ki[k*DD+d];
    red[d] = r*r + im*im;
    __syncthreads();
    for (int s = 64; s > 0; s >>= 1){ if (d < s) red[d] += red[d+s]; __syncthreads(); }
    float nrm = fmaxf(sqrtf(red[0]), 1e-12f);
    Vr[k*DD+d] = r/nrm; Vi[k*DD+d] = im/nrm;
  } else {
    int i = blk - 256;
    float v = Uh[i*DD + d];
    ushort_t h, l; split2(v, h, l);
    PpH[i*DD + d] = h;  PpL[i*DD + d] = l;
    PTh[d*DD + i] = h;  PTl[d*DD + i] = l;
  }
}

// ---- pow2: G^{2^s}, s=1..5 ----
__global__ __launch_bounds__(256,1) void k_pow2(ushort_t* PpH, ushort_t* PpL,
                                                ushort_t* PTh, ushort_t* PTl){
  __shared__ ushort_t Ah[128*SP], Al[128*SP], Bh[128*SP], Bl[128*SP];
  int tid = threadIdx.x;
  int w = tid >> 6, lane = tid & 63, gma = lane & 15, q = lane >> 4;
  int row0 = 64*(w >> 1), col0 = 64*(w & 1);
  lds_load_mat<256>(Ah, PpH, tid);
  lds_load_mat<256>(Al, PpL, tid);
  lds_load_mat<256>(Bh, PTh, tid);
  lds_load_mat<256>(Bl, PTl, tid);
  __syncthreads();
  for (int s = 1; s <= 5; s++){
    float4v acc[16];
    #pragma unroll
    for (int i = 0; i < 16; i++) acc[i] = (float4v){0.f,0.f,0.f,0.f};
    gemm_t<4,4,true,true>(Ah, Al, Bh, Bl, acc, row0, col0, gma, q);
    __syncthreads();
    emit_plain_lds44(acc, Ah, Al, row0, col0, gma, q);
    emit_split44(acc, Bh, Bl, SP, row0, col0, gma, q);
    size_t slot = (size_t)s * 16384;
    emit_split44(acc, PTh + slot, PTl + slot, 128, row0, col0, gma, q);
    #pragma unroll
    for (int R = 0; R < 4; R++)
      #pragma unroll
      for (int C = 0; C < 4; C++){
        int c = col0 + 16*C + gma, r0 = row0 + 16*R + 4*q;
        #pragma unroll
        for (int j = 0; j < 4; j++){
          ushort_t h, l; split2(acc[R*4+C][j], h, l);
          PpH[slot + (size_t)(r0+j)*128 + c] = h;
          PpL[slot + (size_t)(r0+j)*128 + c] = l;
        }
      }
    __syncthreads();
  }
}

// ---- gchain ----
__global__ __launch_bounds__(256,1) void k_gchain(const ushort_t* PpH, const ushort_t* PpL,
                                                  const ushort_t* PTh, const ushort_t* PTl,
                                                  ushort_t* GTh, ushort_t* GTl){
  __shared__ ushort_t Ah[128*SP], Al[128*SP], Bh[128*SP], Bl[128*SP];
  int t = blockIdx.x;
  int tid = threadIdx.x;
  int w = tid >> 6, lane = tid & 63, gma = lane & 15, q = lane >> 4;
  int row0 = 64*(w >> 1), col0 = 64*(w & 1);
  size_t gslot = (size_t)t * 16384;
  if (t == 0){
    for (int i = tid*4; i < 16384; i += 1024){
      int r = i >> 7, k = i & 127;
      ushort4 zz; zz.x = zz.y = zz.z = zz.w = 0;
      *(ushort4*)&GTl[gslot + i] = zz;
      ushort4 oh;
      oh.x = (r == (k+0)) ? (ushort_t)0x3F80 : (ushort_t)0;
      oh.y = (r == (k+1)) ? (ushort_t)0x3F80 : (ushort_t)0;
      oh.z = (r == (k+2)) ? (ushort_t)0x3F80 : (ushort_t)0;
      oh.w = (r == (k+3)) ? (ushort_t)0x3F80 : (ushort_t)0;
      *(ushort4*)&GTh[gslot + i] = oh;
    }
    return;
  }
  int b0 = __ffs(t) - 1;
  int rem = t & ~(1 << b0);
  if (rem == 0){
    size_t ps = (size_t)b0 * 16384;
    for (int i = tid*4; i < 16384; i += 1024){
      *(ushort4*)&GTh[gslot + i] = *(const ushort4*)&PTh[ps + i];
      *(ushort4*)&GTl[gslot + i] = *(const ushort4*)&PTl[ps + i];
    }
    return;
  }
  lds_load_mat<256>(Ah, PpH + (size_t)b0*16384, tid);
  lds_load_mat<256>(Al, PpL + (size_t)b0*16384, tid);
  while (rem){
    int k = __ffs(rem) - 1;
    rem &= ~(1 << k);
    lds_load_mat<256>(Bh, PTh + (size_t)k*16384, tid);
    lds_load_mat<256>(Bl, PTl + (size_t)k*16384, tid);
    __syncthreads();
    float4v acc[16];
    #pragma unroll
    for (int i = 0; i < 16; i++) acc[i] = (float4v){0.f,0.f,0.f,0.f};
    gemm_t<4,4,true,true>(Ah, Al, Bh, Bl, acc, row0, col0, gma, q);
    __syncthreads();
    if (rem){
      emit_plain_lds44(acc, Ah, Al, row0, col0, gma, q);
      __syncthreads();
    } else {
      emit_split44(acc, GTh + gslot, GTl + gslot, 128, row0, col0, gma, q);
    }
  }
}

// ---- precompMW ----
__global__ __launch_bounds__(256,1) void k_precompMW(const ushort_t* GTh, const ushort_t* GTl,
                                                     const ushort_t* UxTh, const ushort_t* UxTl,
                                                     const float* Vr, const float* Vi,
                                                     ushort_t* Mh, ushort_t* Wh){
  __shared__ ushort_t Bh[128*SP], Bl[128*SP], Ah[128*SP], Al[128*SP];
  int blk = blockIdx.x;
  int tid = threadIdx.x;
  int w = tid >> 6, lane = tid & 63, gma = lane & 15, q = lane >> 4;
  int row0 = 64*(w >> 1), col0 = 64*(w & 1);
  if (blk < 60){
    int t = blk;
    lds_load_mat<256>(Bh, GTh + (size_t)t*16384, tid);
    lds_load_mat<256>(Bl, GTl + (size_t)t*16384, tid);
    lds_load_mat<256>(Ah, UxTh, tid);
    lds_load_mat<256>(Al, UxTl, tid);
    __syncthreads();
    float4v acc[16];
    #pragma unroll
    for (int i = 0; i < 16; i++) acc[i] = (float4v){0.f,0.f,0.f,0.f};
    gemm_t<4,4,true,true>(Ah, Al, Bh, Bl, acc, row0, col0, gma, q);
    __syncthreads();
    emit_split44(acc, Ah, Al, SP, row0, col0, gma, q);
    __syncthreads();
    #pragma unroll
    for (int i = 0; i < 16; i++) acc[i] = (float4v){0.f,0.f,0.f,0.f};
    gemm_t<4,4,true,true>(Bh, Bl, Ah, Al, acc, row0, col0, gma, q);
    #pragma unroll
    for (int R = 0; R < 4; R++)
      #pragma unroll
      for (int C = 0; C < 4; C++){
        int c = col0 + 16*C + gma, r0 = row0 + 16*R + 4*q;
        uint2 o;
        o.x = f2bfpk(acc[R*4+C][0], acc[R*4+C][1]);
        o.y = f2bfpk(acc[R*4+C][2], acc[R*4+C][3]);
        *(uint2*)&Mh[(size_t)t*16384 + c*128 + r0] = o;
      }
  } else {
    int bx = blk - 60;
    int t = bx >> 1, which = bx & 1;
    lds_load_mat<256>(Ah, GTh + (size_t)t*16384, tid);
    lds_load_mat<256>(Al, GTl + (size_t)t*16384, tid);
    const float* V = which ? Vi : Vr;
    for (int i = tid; i < 16384; i += 256){
      int r = i >> 7, k = i & 127;
      ushort_t h, l; split2(V[i], h, l);
      Bh[r*SP + k] = h; Bl[r*SP + k] = l;
    }
    __syncthreads();
    float4v acc[16];
    #pragma unroll
    for (int i = 0; i < 16; i++) acc[i] = (float4v){0.f,0.f,0.f,0.f};
    gemm_t<4,4,true,true>(Ah, Al, Bh, Bl, acc, row0, col0, gma, q);
    #pragma unroll
    for (int R = 0; R < 4; R++)
      #pragma unroll
      for (int C = 0; C < 4; C++){
        int c = col0 + 16*C + gma, r0 = row0 + 16*R + 4*q;
        uint2 o;
        o.x = f2bfpk(acc[R*4+C][0], acc[R*4+C][1]);
        o.y = f2bfpk(acc[R*4+C][2], acc[R*4+C][3]);
        *(uint2*)&Wh[(size_t)bx*16384 + c*128 + r0] = o;
      }
  }
}

// ---- prep (fused qtrans) ----
__global__ __launch_bounds__(128) void k_prep(
    const float* x0, const float* x1, const float* x2, const float* smask,
    const float* Wp0, const float* bp0, const float* Wp1, const float* bp1,
    const float* Wp2, const float* bp2, const float* freq, const float* phem,
    const float* Ux, float* Q, float* Wgt)
{
  __shared__ float xs[768+74+35];
  __shared__ float red[DD];
  __shared__ float nrm3[3];
  __shared__ float ps[6][DD];
  int bt = blockIdx.x; int t = bt % DT;
  int d = threadIdx.x;
  const float* r0 = x0 + (size_t)bt*768;
  for (int k = d; k < 768; k += DD) xs[k] = r0[k];
  const float* r1 = x1 + (size_t)bt*74;
  if (d < 74) xs[768+d] = r1[d];
  const float* r2 = x2 + (size_t)bt*35;
  if (d < 35) xs[768+74+d] = r2[d];
  __syncthreads();
  float rep[3];
  { float acc = bp0[d]; for (int k = 0; k < 768; k++) acc += xs[k]*Wp0[k*DD+d]; rep[0] = fmaxf(acc, 0.f); }
  { float acc = bp1[d]; for (int k = 0; k < 74; k++) acc += xs[768+k]*Wp1[k*DD+d]; rep[1] = fmaxf(acc, 0.f); }
  { float acc = bp2[d]; for (int k = 0; k < 35; k++) acc += xs[768+74+k]*Wp2[k*DD+d]; rep[2] = fmaxf(acc, 0.f); }
  for (int m = 0; m < 3; m++){
    red[d] = rep[m]*rep[m];
    __syncthreads();
    for (int s = 64; s > 0; s >>= 1){ if (d < s) red[d] += red[d+s]; __syncthreads(); }
    if (d == 0) nrm3[m] = sqrtf(red[0]);
    __syncthreads();
  }
  float n0 = nrm3[0], n1 = nrm3[1], n2 = nrm3[2];
  float mx = fmaxf(n0, fmaxf(n1, n2));
  float e0 = expf(n0-mx), e1 = expf(n1-mx), e2 = expf(n2-mx);
  float einv = 1.f/(e0+e1+e2);
  if (d < 3) Wgt[bt*3+d] = (d==0?e0:(d==1?e1:e2))*einv;
  float s0 = smask[bt*2], s1 = smask[bt*2+1];
  int id = (s1 > s0) ? 1 : 0;
  float ph = (float)t * freq[id*DD+d] + phem[id*DD+d];
  float cp = cosf(ph), sp = sinf(ph);
  for (int m = 0; m < 3; m++){
    float a = rep[m] / fmaxf(nrm3[m], 1e-12f);
    ps[m][d]   = a*cp;
    ps[3+m][d] = a*sp;
  }
  __syncthreads();
  float qv[6] = {0.f,0.f,0.f,0.f,0.f,0.f};
  const float* uxr = Ux + (size_t)d*DD;
  for (int p = 0; p < DD; p++){
    float u = uxr[p];
    #pragma unroll
    for (int j = 0; j < 6; j++) qv[j] += u * ps[j][p];
  }
  #pragma unroll
  for (int j = 0; j < 6; j++)
    Q[((size_t)(j*BT) + bt)*DD + d] = qv[j];
}

// ---- conjL1 (256 thr, 4 blk/CU): X via rank-6 MFMA, S <- G^T X G, GT global ----
__global__ __launch_bounds__(256,4) void k_conjL1(ushort_t* S, const ushort_t* GTh,
                                                  const float* Q, const float* Wgt){
  __shared__ ushort_t Xs[128*SP];
  __shared__ float wl[3];
  ushort_t* Bstage = Xs;
  int blk = blockIdx.x;            // (t*DB+b)*2+ri
  int ri = blk & 1, tb = blk >> 1;
  int t = tb >> 5, b = tb & 31;
  int bt_in = b*DT + t;
  size_t slot = (size_t)blk * 16384;
  const ushort_t* GT_g = GTh + (size_t)t*16384;
  int tid = threadIdx.x;
  int w = tid >> 6, lane = tid & 63, gma = lane & 15, q = lane >> 4;
  int row0 = 64*(w >> 1), col0 = 64*(w & 1);
  for (int i = tid*4; i < 128*BSTR; i += 1024){
    ushort4 z; z.x = z.y = z.z = z.w = 0;
    *(ushort4*)&Bstage[i] = z;
  }
  if (tid < 3) wl[tid] = Wgt[bt_in*3 + tid];
  __syncthreads();
  for (int l = tid; l < 6*DD; l += 256){
    int j = l >> 7, r = l & 127;
    Bstage[r*BSTR + j] = f2bf(Q[((size_t)(j*BT) + bt_in)*DD + r]);
  }
  __syncthreads();
  float4v acc[16];
  {
    float w0 = wl[0], w1 = wl[1], w2 = wl[2];
    bf16x8 aF[4], bF[4];
    #pragma unroll
    for (int R = 0; R < 4; R++){
      int r = row0 + 16*R + gma;
      bf16x8 braw = *(const bf16x8*)&Bstage[r*BSTR + q*8];
      const ushort_t* bu = (const ushort_t*)&braw;
      union { ushort_t u[8]; bf16x8 v; } au;
      #pragma unroll
      for (int j = 0; j < 8; j++) au.u[j] = 0;
      if (q == 0){
        float b0 = bf2f(bu[0]), b1 = bf2f(bu[1]), b2 = bf2f(bu[2]);
        float b3 = bf2f(bu[3]), b4 = bf2f(bu[4]), b5 = bf2f(bu[5]);
        if (ri == 0){
          au.u[0] = f2bf(w0*b0); au.u[1] = f2bf(w1*b1); au.u[2] = f2bf(w2*b2);
          au.u[3] = f2bf(w0*b3); au.u[4] = f2bf(w1*b4); au.u[5] = f2bf(w2*b5);
        } else {
          au.u[0] = f2bf(-w0*b3); au.u[1] = f2bf(-w1*b4); au.u[2] = f2bf(-w2*b5);
          au.u[3] = f2bf( w0*b0); au.u[4] = f2bf( w1*b1); au.u[5] = f2bf( w2*b2);
        }
      }
      aF[R] = au.v;
    }
    #pragma unroll
    for (int C = 0; C < 4; C++){
      int c = col0 + 16*C + gma;
      bF[C] = *(const bf16x8*)&Bstage[c*BSTR + q*8];
    }
    #pragma unroll
    for (int i = 0; i < 16; i++) acc[i] = (float4v){0.f,0.f,0.f,0.f};
    #pragma unroll
    for (int R = 0; R < 4; R++)
      #pragma unroll
      for (int C = 0; C < 4; C++)
        acc[R*4+C] = __builtin_amdgcn_mfma_f32_16x16x32_bf16(aF[R], bF[C], acc[R*4+C], 0, 0, 0);
  }
  __syncthreads();
  emit_t<4,4>(acc, Xs, SP, row0, col0, gma, q);              // Xs = X (true)
  __syncthreads();
  #pragma unroll
  for (int i = 0; i < 16; i++) acc[i] = (float4v){0.f,0.f,0.f,0.f};
  gemm_bg<4,4>(Xs, GT_g, acc, row0, col0, gma, q);           // T = X*G
  __syncthreads();
  emit_t<4,4>(acc, Xs, SP, row0, col0, gma, q);              // Xs = T^T
  __syncthreads();
  #pragma unroll
  for (int i = 0; i < 16; i++) acc[i] = (float4v){0.f,0.f,0.f,0.f};
  gemm_bg<4,4>(Xs, GT_g, acc, row0, col0, gma, q);           // Y^T
  __syncthreads();
  emit_t<4,4>(acc, Xs, SP, row0, col0, gma, q);              // Xs = Y (true)
  __syncthreads();
  lds_store_mat<256>(S + slot, Xs, tid);
}

// ---- prefix ----
__global__ __launch_bounds__(256) void k_prefix(ushort_t* S, const float* lamp){
  int blk = blockIdx.x;
  int chain = blk >> 4, slab = blk & 15;
  int tid = threadIdx.x;
  size_t off = (size_t)slab*1024 + tid*4;
  float lam = lamp[0];
  float a0=0.f, a1=0.f, a2=0.f, a3=0.f;
  size_t addr = (size_t)chain*16384 + off;
  const size_t step = (size_t)64*16384;
  ushort4 nxt = *(const ushort4*)&S[addr];
  for (int t = 0; t < DT; t++){
    ushort4 u = nxt;
    if (t < DT-1) nxt = *(const ushort4*)&S[addr + step];
    a0 = lam*a0 + bf2f(u.x); a1 = lam*a1 + bf2f(u.y);
    a2 = lam*a2 + bf2f(u.z); a3 = lam*a3 + bf2f(u.w);
    uint2 o; o.x = f2bfpk(a0, a1); o.y = f2bfpk(a2, a3);
    *(uint2*)&S[addr] = o;
    addr += step;
  }
}

// ---- conjmid (256 thr, 4 blk/CU): S <- (1-l) M S M^T + c_t I, M global ----
__global__ __launch_bounds__(256,4) void k_conjmid(ushort_t* S, const ushort_t* Mh,
                                                   const float* lamp){
  __shared__ ushort_t Zs[128*SP];
  int blk = blockIdx.x;
  int t = blk >> 6, ri = blk & 1;
  size_t slot = (size_t)blk * 16384;
  const ushort_t* M_g = Mh + (size_t)t*16384;
  int tid = threadIdx.x;
  int w = tid >> 6, lane = tid & 63, gma = lane & 15, q = lane >> 4;
  int row0 = 64*(w >> 1), col0 = 64*(w & 1);
  lds_load_mat<256>(Zs, S + slot, tid);
  __syncthreads();
  float lam = lamp[0];
  float oml = 1.f - lam;
  float ct = (ri == 0) ? (powf(lam, (float)(t+1)) / 128.f) : 0.f;
  float4v acc[16];
  #pragma unroll
  for (int i = 0; i < 16; i++) acc[i] = (float4v){0.f,0.f,0.f,0.f};
  gemm_bg<4,4>(Zs, M_g, acc, row0, col0, gma, q);
  __syncthreads();
  emit_t<4,4>(acc, Zs, SP, row0, col0, gma, q);
  __syncthreads();
  #pragma unroll
  for (int i = 0; i < 16; i++) acc[i] = (float4v){0.f,0.f,0.f,0.f};
  gemm_bg<4,4>(Zs, M_g, acc, row0, col0, gma, q);
  __syncthreads();
  #pragma unroll
  for (int R = 0; R < 4; R++)
    #pragma unroll
    for (int C = 0; C < 4; C++){
      int c = col0 + 16*C + gma, r0 = row0 + 16*R + 4*q;
      float v0 = oml*acc[R*4+C][0] + ((c == r0+0) ? ct : 0.f);
      float v1 = oml*acc[R*4+C][1] + ((c == r0+1) ? ct : 0.f);
      float v2 = oml*acc[R*4+C][2] + ((c == r0+2) ? ct : 0.f);
      float v3 = oml*acc[R*4+C][3] + ((c == r0+3) ? ct : 0.f);
      uint2 o; o.x = f2bfpk(v0, v1); o.y = f2bfpk(v2, v3);
      *(uint2*)&Zs[(size_t)c*SP + r0] = o;
    }
  __syncthreads();
  lds_store_mat<256>(S + slot, Zs, tid);
}

// ---- meas (512 thr, per tb): 3 GEMM+diag phases, W via global L2 frags ----
__global__ __launch_bounds__(512,4) void k_meas(const ushort_t* S, const ushort_t* Wh,
                                                const float* lamp, float* Probs){
  __shared__ ushort_t buf0[128*SP], buf1[128*SP];
  __shared__ float Pd[DD];
  int tb = blockIdx.x;
  int t = tb >> 5;
  int tid = threadIdx.x;
  int w = tid >> 6, lane = tid & 63, gma = lane & 15, q = lane >> 4;
  int row0 = 32*(w >> 1), col0 = 64*(w & 1);   // RT=2, CT=4 over 8 waves
  size_t slot_r = (size_t)(tb*2) * 16384;
  const ushort_t* Wr_g = Wh + (size_t)(t*2) * 16384;
  const ushort_t* Wi_g = Wr_g + 16384;
  const ushort_t* Si_g = S + slot_r + 16384;
  // stage Sr; prefetch Si into regs
  ushort4 sireg[8];
  #pragma unroll
  for (int j = 0; j < 8; j++)
    sireg[j] = ((const ushort4*)Si_g)[tid + j*512];
  lds_load_mat<512>(buf0, S + slot_r, tid);
  if (tid < DD) Pd[tid] = 0.f;
  __syncthreads();
  float4v acc[8];
  // phase 1: D1'[m][n] = sum_k Sr[m,k] Wr[n,k] -> emit_t => buf1[n][m] (k-major rows)
  #pragma unroll
  for (int i = 0; i < 8; i++) acc[i] = (float4v){0.f,0.f,0.f,0.f};
  gemm_bg<2,4>(buf0, Wr_g, acc, row0, col0, gma, q);
  __syncthreads();
  emit_t<2,4>(acc, buf1, SP, row0, col0, gma, q);
  __syncthreads();
  // diag1: E[n] = sum_m buf1[n][m]*Wr[n,m], wave w -> tile rows 16w..
  {
    int rr = 16*w + gma;
    float4v a1 = (float4v){0.f,0.f,0.f,0.f};
    #pragma unroll
    for (int ks = 0; ks < 4; ks++){
      int ko = ks*32 + q*8;
      bf16x8 aF = *(const bf16x8*)&buf1[rr*SP + ko];
      bf16x8 bF = *(const bf16x8*)&Wr_g[(size_t)rr*128 + ko];
      a1 = __builtin_amdgcn_mfma_f32_16x16x32_bf16(aF, bF, a1, 0, 0, 0);
    }
    if ((gma >> 2) == q) atomicAdd(&Pd[rr], a1[gma & 3]);
  }
  __syncthreads();
  // phase 2: D2' with Wi
  #pragma unroll
  for (int i = 0; i < 8; i++) acc[i] = (float4v){0.f,0.f,0.f,0.f};
  gemm_bg<2,4>(buf0, Wi_g, acc, row0, col0, gma, q);
  __syncthreads();
  emit_t<2,4>(acc, buf1, SP, row0, col0, gma, q);
  // Sr dead: dump Si regs into buf0
  #pragma unroll
  for (int j = 0; j < 8; j++){
    int e = (tid + j*512)*4;
    *(ushort4*)&buf0[(e >> 7)*SP + (e & 127)] = sireg[j];
  }
  __syncthreads();
  // diag2
  {
    int rr = 16*w + gma;
    float4v a1 = (float4v){0.f,0.f,0.f,0.f};
    #pragma unroll
    for (int ks = 0; ks < 4; ks++){
      int ko = ks*32 + q*8;
      bf16x8 aF = *(const bf16x8*)&buf1[rr*SP + ko];
      bf16x8 bF = *(const bf16x8*)&Wi_g[(size_t)rr*128 + ko];
      a1 = __builtin_amdgcn_mfma_f32_16x16x32_bf16(aF, bF, a1, 0, 0, 0);
    }
    if ((gma >> 2) == q) atomicAdd(&Pd[rr], a1[gma & 3]);
  }
  __syncthreads();
  // phase 3: D3'[m][n] = sum_k Si[m,k] Wi[n,k] -> buf1[n][m]
  #pragma unroll
  for (int i = 0; i < 8; i++) acc[i] = (float4v){0.f,0.f,0.f,0.f};
  gemm_bg<2,4>(buf0, Wi_g, acc, row0, col0, gma, q);
  __syncthreads();
  emit_t<2,4>(acc, buf1, SP, row0, col0, gma, q);
  __syncthreads();
  // diag3: coefficient -2 (buf1 row n = (Wi Si^T)[n,:]; -2*that = +2 (Wi Si Wr^T)_nn)
  {
    int rr = 16*w + gma;
    float4v a1 = (float4v){0.f,0.f,0.f,0.f};
    #pragma unroll
    for (int ks = 0; ks < 4; ks++){
      int ko = ks*32 + q*8;
      bf16x8 aF = *(const bf16x8*)&buf1[rr*SP + ko];
      bf16x8 bF = *(const bf16x8*)&Wr_g[(size_t)rr*128 + ko];
      a1 = __builtin_amdgcn_mfma_f32_16x16x32_bf16(aF, bF, a1, 0, 0, 0);
    }
    if ((gma >> 2) == q) atomicAdd(&Pd[rr], -2.f*a1[gma & 3]);
  }
  __syncthreads();
  if (tid < DD){
    float lam = lamp[0];
    float ct = powf(lam, (float)(t+1)) / 128.f;
    Probs[(size_t)tb*DD + tid] = (1.f - lam)*Pd[tid] + ct;
  }
}

// ---- head ----
__global__ __launch_bounds__(64) void k_head(const float* Probs, const float* W1, const float* b1,
                        const float* W2, const float* b2, float* out)
{
  __shared__ float ps[DD];
  __shared__ float hid[64];
  __shared__ float ov[4];
  int tb = blockIdx.x;
  int tid = threadIdx.x;
  ps[tid] = Probs[(size_t)tb*DD + tid];
  ps[tid+64] = Probs[(size_t)tb*DD + 64 + tid];
  __syncthreads();
  float acc = b1[tid];
  for (int dd = 0; dd < DD; dd++) acc += ps[dd]*W1[dd*64 + tid];
  hid[tid] = fmaxf(acc, 0.f);
  __syncthreads();
  if (tid < 4){
    float o = b2[tid];
    for (int j = 0; j < 64; j++) o += hid[j]*W2[j*4 + tid];
    ov[tid] = tanhf(o);
  }
  __syncthreads();
  if (tid == 0){
    float m = fmaxf(fmaxf(ov[0],ov[1]), fmaxf(ov[2],ov[3]));
    float lse = logf(expf(ov[0]-m)+expf(ov[1]-m)+expf(ov[2]-m)+expf(ov[3]-m));
    int t = tb >> 5, b = tb & 31;
    float* o = out + ((size_t)(b*DT + t))*4;
    o[0] = ov[0]-m-lse; o[1] = ov[1]-m-lse;
    o[2] = ov[2]-m-lse; o[3] = ov[3]-m-lse;
  }
}

extern "C" void kernel_launch(void* const* d_in, const int* in_sizes, int n_in,
                              void* d_out, int out_size, void* d_ws, size_t ws_size,
                              hipStream_t stream)
{
  const float* x0    = (const float*)d_in[0];
  const float* x1    = (const float*)d_in[1];
  const float* x2    = (const float*)d_in[2];
  const float* smask = (const float*)d_in[3];
  const float* Wp0   = (const float*)d_in[4];
  const float* bp0   = (const float*)d_in[5];
  const float* Wp1   = (const float*)d_in[6];
  const float* bp1   = (const float*)d_in[7];
  const float* Wp2   = (const float*)d_in[8];
  const float* bp2   = (const float*)d_in[9];
  const float* freq  = (const float*)d_in[10];
  const float* phem  = (const float*)d_in[11];
  const float* Ux    = (const float*)d_in[12];
  const float* Uh    = (const float*)d_in[13];
  const float* lamp  = (const float*)d_in[14];
  const float* kr    = (const float*)d_in[15];
  const float* ki    = (const float*)d_in[16];
  const float* W1    = (const float*)d_in[17];
  const float* b1    = (const float*)d_in[18];
  const float* W2    = (const float*)d_in[19];
  const float* b2    = (const float*)d_in[20];

  char* ws = (char*)d_ws;
  auto alignup = [](size_t x){ return (x + 255) & ~(size_t)255; };
  size_t off = 0;
  ushort_t* S   = (ushort_t*)(ws + off); off = alignup(off + (size_t)3840*16384*sizeof(ushort_t));
  float* Qbuf   = (float*)(ws + off);    off = alignup(off + (size_t)6*BT*DD*sizeof(float));
  float* Wgt    = (float*)(ws + off);    off = alignup(off + (size_t)BT*3*sizeof(float));
  float* Vr     = (float*)(ws + off);    off = alignup(off + (size_t)DD*DD*sizeof(float));
  float* Vi     = (float*)(ws + off);    off = alignup(off + (size_t)DD*DD*sizeof(float));
  ushort_t* UxTh = (ushort_t*)(ws + off); off = alignup(off + (size_t)DD*DD*sizeof(ushort_t));
  ushort_t* UxTl = (ushort_t*)(ws + off); off = alignup(off + (size_t)DD*DD*sizeof(ushort_t));
  float* Probs  = (float*)(ws + off);    off = alignup(off + (size_t)BT*DD*sizeof(float));
  ushort_t* PpH = (ushort_t*)(ws + off); off = alignup(off + (size_t)6*16384*sizeof(ushort_t));
  ushort_t* PpL = (ushort_t*)(ws + off); off = alignup(off + (size_t)6*16384*sizeof(ushort_t));
  ushort_t* PTh = (ushort_t*)(ws + off); off = alignup(off + (size_t)6*16384*sizeof(ushort_t));
  ushort_t* PTl = (ushort_t*)(ws + off); off = alignup(off + (size_t)6*16384*sizeof(ushort_t));
  ushort_t* Mh  = (ushort_t*)(ws + off); off = alignup(off + (size_t)60*16384*sizeof(ushort_t));
  ushort_t* Wmh = (ushort_t*)(ws + off); off = alignup(off + (size_t)120*16384*sizeof(ushort_t));
  ushort_t* GTh = (ushort_t*)(ws + off); off = alignup(off + (size_t)60*16384*sizeof(ushort_t));
  ushort_t* GTl = (ushort_t*)(ws + off); off = alignup(off + (size_t)60*16384*sizeof(ushort_t));
  (void)ws_size; (void)in_sizes; (void)n_in; (void)out_size;

  k_small<<<384, 128, 0, stream>>>(Ux, Uh, kr, ki, UxTh, UxTl, Vr, Vi, PpH, PpL, PTh, PTl);
  k_prep<<<BT, 128, 0, stream>>>(x0, x1, x2, smask, Wp0, bp0, Wp1, bp1, Wp2, bp2, freq, phem, Ux, Qbuf, Wgt);
  k_pow2<<<1, 256, 0, stream>>>(PpH, PpL, PTh, PTl);
  k_gchain<<<60, 256, 0, stream>>>(PpH, PpL, PTh, PTl, GTh, GTl);
  k_precompMW<<<180, 256, 0, stream>>>(GTh, GTl, UxTh, UxTl, Vr, Vi, Mh, Wmh);
  k_conjL1<<<3840, 256, 0, stream>>>(S, GTh, Qbuf, Wgt);
  k_prefix<<<1024, 256, 0, stream>>>(S, lamp);
  k_conjmid<<<3840, 256, 0, stream>>>(S, Mh, lamp);
  k_prefix<<<1024, 256, 0, stream>>>(S, lamp);
  k_meas<<<1920, 512, 0, stream>>>(S, Wmh, lamp, Probs);
  k_head<<<BT, 64, 0, stream>>>(Probs, W1, b1, W2, b2, (float*)d_out);
}

// Round 9
// 563.574 us; speedup vs baseline: 1.1695x; 1.1695x over previous
//
#include <hip/hip_runtime.h>

// QMN B=32,T=60,D=128. Round 9 = r7 structure (global-B experiment of r8
// REVERTED: L2-latency in the MFMA chain regressed meas 106->130 and conj).
// Single change vs r7: k_meas at 512 thr (8 waves, same 70KB LDS) -> 2 blk/CU
// = 16 waves/CU (was 8). Tiles RT=2/CT=4; diag tiles 1/wave; cross 2x2/wave.

#define DB 32
#define DT 60
#define DD 128
#define BT (DB*DT)
#define SP 136
#define BSTR 36

typedef unsigned short ushort_t;
typedef __attribute__((ext_vector_type(8))) __bf16 bf16x8;
typedef __attribute__((ext_vector_type(4))) float  float4v;

__device__ __forceinline__ float bf2f(ushort_t u){
  union { unsigned int i; float f; } x; x.i = ((unsigned int)u) << 16; return x.f;
}
__device__ __forceinline__ ushort_t f2bf(float f){
  union { float f; unsigned int i; } x; x.f = f;
  unsigned int lsb = (x.i >> 16) & 1u;
  return (ushort_t)((x.i + 0x7FFFu + lsb) >> 16);
}
__device__ __forceinline__ unsigned int f2bfpk(float a, float b){
#if defined(__gfx950__) && __has_builtin(__builtin_amdgcn_cvt_pk_bf16_f32)
  auto v = __builtin_amdgcn_cvt_pk_bf16_f32(a, b);
  unsigned int r; __builtin_memcpy(&r, &v, 4); return r;
#else
  return (unsigned int)f2bf(a) | ((unsigned int)f2bf(b) << 16);
#endif
}
__device__ __forceinline__ void split2(float v, ushort_t& h, ushort_t& l){
  h = f2bf(v); l = f2bf(v - bf2f(h));
}

// D[m][n] = sum_k A[m][k]*B[n][k]; wave tile rows row0+16R+.., cols col0+16C+..
template<int RT, int CT, bool ALO, bool BLO>
__device__ __forceinline__ void gemm_t(const ushort_t* Ah, const ushort_t* Al,
                                       const ushort_t* Bh, const ushort_t* Bl,
                                       float4v* acc, int row0, int col0, int gma, int q)
{
  for (int ks = 0; ks < 4; ks++){
    int ko = ks*32 + q*8;
    bf16x8 aF[RT], aL[RT], bF[CT], bL[CT];
    #pragma unroll
    for (int R = 0; R < RT; R++){
      int row = row0 + 16*R + gma;
      aF[R] = *(const bf16x8*)&Ah[row*SP + ko];
      if (ALO) aL[R] = *(const bf16x8*)&Al[row*SP + ko];
    }
    #pragma unroll
    for (int C = 0; C < CT; C++){
      int row = col0 + 16*C + gma;
      bF[C] = *(const bf16x8*)&Bh[row*SP + ko];
      if (BLO) bL[C] = *(const bf16x8*)&Bl[row*SP + ko];
    }
    #pragma unroll
    for (int R = 0; R < RT; R++)
      #pragma unroll
      for (int C = 0; C < CT; C++){
        float4v c = acc[R*CT+C];
        c = __builtin_amdgcn_mfma_f32_16x16x32_bf16(aF[R], bF[C], c, 0, 0, 0);
        if (BLO) c = __builtin_amdgcn_mfma_f32_16x16x32_bf16(aF[R], bL[C], c, 0, 0, 0);
        if (ALO) c = __builtin_amdgcn_mfma_f32_16x16x32_bf16(aL[R], bF[C], c, 0, 0, 0);
        acc[R*CT+C] = c;
      }
  }
}

// transposed store computed(m,n) -> dst[n*stride + m] (single bf16)
template<int RT, int CT>
__device__ __forceinline__ void emit_t(const float4v* acc, ushort_t* dst, int stride,
                                       int row0, int col0, int gma, int q){
  #pragma unroll
  for (int R = 0; R < RT; R++)
    #pragma unroll
    for (int C = 0; C < CT; C++){
      int c = col0 + 16*C + gma, r0 = row0 + 16*R + 4*q;
      uint2 o;
      o.x = f2bfpk(acc[R*CT+C][0], acc[R*CT+C][1]);
      o.y = f2bfpk(acc[R*CT+C][2], acc[R*CT+C][3]);
      *(uint2*)&dst[(size_t)c*stride + r0] = o;
    }
}
__device__ __forceinline__ void emit_split44(const float4v* acc, ushort_t* dh, ushort_t* dl, int stride,
                                             int row0, int col0, int gma, int q){
  #pragma unroll
  for (int R = 0; R < 4; R++)
    #pragma unroll
    for (int C = 0; C < 4; C++){
      int c = col0 + 16*C + gma, r0 = row0 + 16*R + 4*q;
      ushort4 hh, ll;
      split2(acc[R*4+C][0], hh.x, ll.x); split2(acc[R*4+C][1], hh.y, ll.y);
      split2(acc[R*4+C][2], hh.z, ll.z); split2(acc[R*4+C][3], hh.w, ll.w);
      *(ushort4*)&dh[(size_t)c*stride + r0] = hh;
      *(ushort4*)&dl[(size_t)c*stride + r0] = ll;
    }
}
__device__ __forceinline__ void emit_plain_lds44(const float4v* acc, ushort_t* dh, ushort_t* dl,
                                                 int row0, int col0, int gma, int q){
  #pragma unroll
  for (int R = 0; R < 4; R++)
    #pragma unroll
    for (int C = 0; C < 4; C++){
      int c = col0 + 16*C + gma, r0 = row0 + 16*R + 4*q;
      #pragma unroll
      for (int j = 0; j < 4; j++){
        ushort_t h, l; split2(acc[R*4+C][j], h, l);
        dh[(size_t)(r0+j)*SP + c] = h;
        dl[(size_t)(r0+j)*SP + c] = l;
      }
    }
}
template<int NT>
__device__ __forceinline__ void lds_load_mat(ushort_t* dst, const ushort_t* src, int tid){
  for (int i = tid*4; i < 16384; i += NT*4){
    int r = i >> 7, k = i & 127;
    *(ushort4*)&dst[r*SP + k] = *(const ushort4*)&src[i];
  }
}
template<int NT>
__device__ __forceinline__ void lds_store_mat(ushort_t* dst, const ushort_t* src, int tid){
  for (int i = tid*4; i < 16384; i += NT*4){
    int r = i >> 7, k = i & 127;
    *(ushort4*)&dst[i] = *(const ushort4*)&src[r*SP + k];
  }
}

// ---- small: prepU | normv | initG ----
__global__ void k_small(const float* Ux, const float* Uh, const float* kr, const float* ki,
                        ushort_t* UxTh, ushort_t* UxTl, float* Vr, float* Vi,
                        ushort_t* PpH, ushort_t* PpL, ushort_t* PTh, ushort_t* PTl){
  int blk = blockIdx.x, d = threadIdx.x;
  if (blk < 128){
    int i = blk;
    float v = Ux[i*DD + d];
    ushort_t h, l; split2(v, h, l);
    UxTh[d*DD + i] = h; UxTl[d*DD + i] = l;
  } else if (blk < 256){
    __shared__ float red[DD];
    int k = blk - 128;
    float r = kr[k*DD+d], im = ki[k*DD+d];
    red[d] = r*r + im*im;
    __syncthreads();
    for (int s = 64; s > 0; s >>= 1){ if (d < s) red[d] += red[d+s]; __syncthreads(); }
    float nrm = fmaxf(sqrtf(red[0]), 1e-12f);
    Vr[k*DD+d] = r/nrm; Vi[k*DD+d] = im/nrm;
  } else {
    int i = blk - 256;
    float v = Uh[i*DD + d];
    ushort_t h, l; split2(v, h, l);
    PpH[i*DD + d] = h;  PpL[i*DD + d] = l;
    PTh[d*DD + i] = h;  PTl[d*DD + i] = l;
  }
}

// ---- pow2: G^{2^s}, s=1..5 ----
__global__ __launch_bounds__(256,1) void k_pow2(ushort_t* PpH, ushort_t* PpL,
                                                ushort_t* PTh, ushort_t* PTl){
  __shared__ ushort_t Ah[128*SP], Al[128*SP], Bh[128*SP], Bl[128*SP];
  int tid = threadIdx.x;
  int w = tid >> 6, lane = tid & 63, gma = lane & 15, q = lane >> 4;
  int row0 = 64*(w >> 1), col0 = 64*(w & 1);
  lds_load_mat<256>(Ah, PpH, tid);
  lds_load_mat<256>(Al, PpL, tid);
  lds_load_mat<256>(Bh, PTh, tid);
  lds_load_mat<256>(Bl, PTl, tid);
  __syncthreads();
  for (int s = 1; s <= 5; s++){
    float4v acc[16];
    #pragma unroll
    for (int i = 0; i < 16; i++) acc[i] = (float4v){0.f,0.f,0.f,0.f};
    gemm_t<4,4,true,true>(Ah, Al, Bh, Bl, acc, row0, col0, gma, q);
    __syncthreads();
    emit_plain_lds44(acc, Ah, Al, row0, col0, gma, q);
    emit_split44(acc, Bh, Bl, SP, row0, col0, gma, q);
    size_t slot = (size_t)s * 16384;
    emit_split44(acc, PTh + slot, PTl + slot, 128, row0, col0, gma, q);
    #pragma unroll
    for (int R = 0; R < 4; R++)
      #pragma unroll
      for (int C = 0; C < 4; C++){
        int c = col0 + 16*C + gma, r0 = row0 + 16*R + 4*q;
        #pragma unroll
        for (int j = 0; j < 4; j++){
          ushort_t h, l; split2(acc[R*4+C][j], h, l);
          PpH[slot + (size_t)(r0+j)*128 + c] = h;
          PpL[slot + (size_t)(r0+j)*128 + c] = l;
        }
      }
    __syncthreads();
  }
}

// ---- gchain ----
__global__ __launch_bounds__(256,1) void k_gchain(const ushort_t* PpH, const ushort_t* PpL,
                                                  const ushort_t* PTh, const ushort_t* PTl,
                                                  ushort_t* GTh, ushort_t* GTl){
  __shared__ ushort_t Ah[128*SP], Al[128*SP], Bh[128*SP], Bl[128*SP];
  int t = blockIdx.x;
  int tid = threadIdx.x;
  int w = tid >> 6, lane = tid & 63, gma = lane & 15, q = lane >> 4;
  int row0 = 64*(w >> 1), col0 = 64*(w & 1);
  size_t gslot = (size_t)t * 16384;
  if (t == 0){
    for (int i = tid*4; i < 16384; i += 1024){
      int r = i >> 7, k = i & 127;
      ushort4 zz; zz.x = zz.y = zz.z = zz.w = 0;
      *(ushort4*)&GTl[gslot + i] = zz;
      ushort4 oh;
      oh.x = (r == (k+0)) ? (ushort_t)0x3F80 : (ushort_t)0;
      oh.y = (r == (k+1)) ? (ushort_t)0x3F80 : (ushort_t)0;
      oh.z = (r == (k+2)) ? (ushort_t)0x3F80 : (ushort_t)0;
      oh.w = (r == (k+3)) ? (ushort_t)0x3F80 : (ushort_t)0;
      *(ushort4*)&GTh[gslot + i] = oh;
    }
    return;
  }
  int b0 = __ffs(t) - 1;
  int rem = t & ~(1 << b0);
  if (rem == 0){
    size_t ps = (size_t)b0 * 16384;
    for (int i = tid*4; i < 16384; i += 1024){
      *(ushort4*)&GTh[gslot + i] = *(const ushort4*)&PTh[ps + i];
      *(ushort4*)&GTl[gslot + i] = *(const ushort4*)&PTl[ps + i];
    }
    return;
  }
  lds_load_mat<256>(Ah, PpH + (size_t)b0*16384, tid);
  lds_load_mat<256>(Al, PpL + (size_t)b0*16384, tid);
  while (rem){
    int k = __ffs(rem) - 1;
    rem &= ~(1 << k);
    lds_load_mat<256>(Bh, PTh + (size_t)k*16384, tid);
    lds_load_mat<256>(Bl, PTl + (size_t)k*16384, tid);
    __syncthreads();
    float4v acc[16];
    #pragma unroll
    for (int i = 0; i < 16; i++) acc[i] = (float4v){0.f,0.f,0.f,0.f};
    gemm_t<4,4,true,true>(Ah, Al, Bh, Bl, acc, row0, col0, gma, q);
    __syncthreads();
    if (rem){
      emit_plain_lds44(acc, Ah, Al, row0, col0, gma, q);
      __syncthreads();
    } else {
      emit_split44(acc, GTh + gslot, GTl + gslot, 128, row0, col0, gma, q);
    }
  }
}

// ---- precompMW ----
__global__ __launch_bounds__(256,1) void k_precompMW(const ushort_t* GTh, const ushort_t* GTl,
                                                     const ushort_t* UxTh, const ushort_t* UxTl,
                                                     const float* Vr, const float* Vi,
                                                     ushort_t* Mh, ushort_t* Wh){
  __shared__ ushort_t Bh[128*SP], Bl[128*SP], Ah[128*SP], Al[128*SP];
  int blk = blockIdx.x;
  int tid = threadIdx.x;
  int w = tid >> 6, lane = tid & 63, gma = lane & 15, q = lane >> 4;
  int row0 = 64*(w >> 1), col0 = 64*(w & 1);
  if (blk < 60){
    int t = blk;
    lds_load_mat<256>(Bh, GTh + (size_t)t*16384, tid);
    lds_load_mat<256>(Bl, GTl + (size_t)t*16384, tid);
    lds_load_mat<256>(Ah, UxTh, tid);
    lds_load_mat<256>(Al, UxTl, tid);
    __syncthreads();
    float4v acc[16];
    #pragma unroll
    for (int i = 0; i < 16; i++) acc[i] = (float4v){0.f,0.f,0.f,0.f};
    gemm_t<4,4,true,true>(Ah, Al, Bh, Bl, acc, row0, col0, gma, q);
    __syncthreads();
    emit_split44(acc, Ah, Al, SP, row0, col0, gma, q);
    __syncthreads();
    #pragma unroll
    for (int i = 0; i < 16; i++) acc[i] = (float4v){0.f,0.f,0.f,0.f};
    gemm_t<4,4,true,true>(Bh, Bl, Ah, Al, acc, row0, col0, gma, q);
    #pragma unroll
    for (int R = 0; R < 4; R++)
      #pragma unroll
      for (int C = 0; C < 4; C++){
        int c = col0 + 16*C + gma, r0 = row0 + 16*R + 4*q;
        uint2 o;
        o.x = f2bfpk(acc[R*4+C][0], acc[R*4+C][1]);
        o.y = f2bfpk(acc[R*4+C][2], acc[R*4+C][3]);
        *(uint2*)&Mh[(size_t)t*16384 + c*128 + r0] = o;
      }
  } else {
    int bx = blk - 60;
    int t = bx >> 1, which = bx & 1;
    lds_load_mat<256>(Ah, GTh + (size_t)t*16384, tid);
    lds_load_mat<256>(Al, GTl + (size_t)t*16384, tid);
    const float* V = which ? Vi : Vr;
    for (int i = tid; i < 16384; i += 256){
      int r = i >> 7, k = i & 127;
      ushort_t h, l; split2(V[i], h, l);
      Bh[r*SP + k] = h; Bl[r*SP + k] = l;
    }
    __syncthreads();
    float4v acc[16];
    #pragma unroll
    for (int i = 0; i < 16; i++) acc[i] = (float4v){0.f,0.f,0.f,0.f};
    gemm_t<4,4,true,true>(Ah, Al, Bh, Bl, acc, row0, col0, gma, q);
    #pragma unroll
    for (int R = 0; R < 4; R++)
      #pragma unroll
      for (int C = 0; C < 4; C++){
        int c = col0 + 16*C + gma, r0 = row0 + 16*R + 4*q;
        uint2 o;
        o.x = f2bfpk(acc[R*4+C][0], acc[R*4+C][1]);
        o.y = f2bfpk(acc[R*4+C][2], acc[R*4+C][3]);
        *(uint2*)&Wh[(size_t)bx*16384 + c*128 + r0] = o;
      }
  }
}

// ---- prep (fused qtrans) ----
__global__ __launch_bounds__(128) void k_prep(
    const float* x0, const float* x1, const float* x2, const float* smask,
    const float* Wp0, const float* bp0, const float* Wp1, const float* bp1,
    const float* Wp2, const float* bp2, const float* freq, const float* phem,
    const float* Ux, float* Q, float* Wgt)
{
  __shared__ float xs[768+74+35];
  __shared__ float red[DD];
  __shared__ float nrm3[3];
  __shared__ float ps[6][DD];
  int bt = blockIdx.x; int t = bt % DT;
  int d = threadIdx.x;
  const float* r0 = x0 + (size_t)bt*768;
  for (int k = d; k < 768; k += DD) xs[k] = r0[k];
  const float* r1 = x1 + (size_t)bt*74;
  if (d < 74) xs[768+d] = r1[d];
  const float* r2 = x2 + (size_t)bt*35;
  if (d < 35) xs[768+74+d] = r2[d];
  __syncthreads();
  float rep[3];
  { float acc = bp0[d]; for (int k = 0; k < 768; k++) acc += xs[k]*Wp0[k*DD+d]; rep[0] = fmaxf(acc, 0.f); }
  { float acc = bp1[d]; for (int k = 0; k < 74; k++) acc += xs[768+k]*Wp1[k*DD+d]; rep[1] = fmaxf(acc, 0.f); }
  { float acc = bp2[d]; for (int k = 0; k < 35; k++) acc += xs[768+74+k]*Wp2[k*DD+d]; rep[2] = fmaxf(acc, 0.f); }
  for (int m = 0; m < 3; m++){
    red[d] = rep[m]*rep[m];
    __syncthreads();
    for (int s = 64; s > 0; s >>= 1){ if (d < s) red[d] += red[d+s]; __syncthreads(); }
    if (d == 0) nrm3[m] = sqrtf(red[0]);
    __syncthreads();
  }
  float n0 = nrm3[0], n1 = nrm3[1], n2 = nrm3[2];
  float mx = fmaxf(n0, fmaxf(n1, n2));
  float e0 = expf(n0-mx), e1 = expf(n1-mx), e2 = expf(n2-mx);
  float einv = 1.f/(e0+e1+e2);
  if (d < 3) Wgt[bt*3+d] = (d==0?e0:(d==1?e1:e2))*einv;
  float s0 = smask[bt*2], s1 = smask[bt*2+1];
  int id = (s1 > s0) ? 1 : 0;
  float ph = (float)t * freq[id*DD+d] + phem[id*DD+d];
  float cp = cosf(ph), sp = sinf(ph);
  for (int m = 0; m < 3; m++){
    float a = rep[m] / fmaxf(nrm3[m], 1e-12f);
    ps[m][d]   = a*cp;
    ps[3+m][d] = a*sp;
  }
  __syncthreads();
  float qv[6] = {0.f,0.f,0.f,0.f,0.f,0.f};
  const float* uxr = Ux + (size_t)d*DD;
  for (int p = 0; p < DD; p++){
    float u = uxr[p];
    #pragma unroll
    for (int j = 0; j < 6; j++) qv[j] += u * ps[j][p];
  }
  #pragma unroll
  for (int j = 0; j < 6; j++)
    Q[((size_t)(j*BT) + bt)*DD + d] = qv[j];
}

// ---- conjL1 (512 thr): X via rank-6 MFMA, S <- G^T X G ----
__global__ __launch_bounds__(512,4) void k_conjL1(ushort_t* S, const ushort_t* GTh,
                                                  const float* Q, const float* Wgt){
  __shared__ ushort_t Bh[128*SP], Xs[128*SP];
  __shared__ float wl[3];
  ushort_t* Bstage = Xs;
  int blk = blockIdx.x;            // (t*DB+b)*2+ri
  int ri = blk & 1, tb = blk >> 1;
  int t = tb >> 5, b = tb & 31;
  int bt_in = b*DT + t;
  size_t slot = (size_t)blk * 16384;
  int tid = threadIdx.x;
  int w = tid >> 6, lane = tid & 63, gma = lane & 15, q = lane >> 4;
  int row0 = 32*(w >> 1), col0 = 64*(w & 1);
  lds_load_mat<512>(Bh, GTh + (size_t)t*16384, tid);
  for (int i = tid*4; i < 128*BSTR; i += 2048){
    ushort4 z; z.x = z.y = z.z = z.w = 0;
    *(ushort4*)&Bstage[i] = z;
  }
  if (tid < 3) wl[tid] = Wgt[bt_in*3 + tid];
  __syncthreads();
  for (int l = tid; l < 6*DD; l += 512){
    int j = l >> 7, r = l & 127;
    Bstage[r*BSTR + j] = f2bf(Q[((size_t)(j*BT) + bt_in)*DD + r]);
  }
  __syncthreads();
  float4v acc[8];
  {
    float w0 = wl[0], w1 = wl[1], w2 = wl[2];
    bf16x8 aF[2], bF[4];
    #pragma unroll
    for (int R = 0; R < 2; R++){
      int r = row0 + 16*R + gma;
      bf16x8 braw = *(const bf16x8*)&Bstage[r*BSTR + q*8];
      const ushort_t* bu = (const ushort_t*)&braw;
      union { ushort_t u[8]; bf16x8 v; } au;
      #pragma unroll
      for (int j = 0; j < 8; j++) au.u[j] = 0;
      if (q == 0){
        float b0 = bf2f(bu[0]), b1 = bf2f(bu[1]), b2 = bf2f(bu[2]);
        float b3 = bf2f(bu[3]), b4 = bf2f(bu[4]), b5 = bf2f(bu[5]);
        if (ri == 0){
          au.u[0] = f2bf(w0*b0); au.u[1] = f2bf(w1*b1); au.u[2] = f2bf(w2*b2);
          au.u[3] = f2bf(w0*b3); au.u[4] = f2bf(w1*b4); au.u[5] = f2bf(w2*b5);
        } else {
          au.u[0] = f2bf(-w0*b3); au.u[1] = f2bf(-w1*b4); au.u[2] = f2bf(-w2*b5);
          au.u[3] = f2bf( w0*b0); au.u[4] = f2bf( w1*b1); au.u[5] = f2bf( w2*b2);
        }
      }
      aF[R] = au.v;
    }
    #pragma unroll
    for (int C = 0; C < 4; C++){
      int c = col0 + 16*C + gma;
      bF[C] = *(const bf16x8*)&Bstage[c*BSTR + q*8];
    }
    #pragma unroll
    for (int i = 0; i < 8; i++) acc[i] = (float4v){0.f,0.f,0.f,0.f};
    #pragma unroll
    for (int R = 0; R < 2; R++)
      #pragma unroll
      for (int C = 0; C < 4; C++)
        acc[R*4+C] = __builtin_amdgcn_mfma_f32_16x16x32_bf16(aF[R], bF[C], acc[R*4+C], 0, 0, 0);
  }
  __syncthreads();
  emit_t<2,4>(acc, Xs, SP, row0, col0, gma, q);              // Xs = X (true)
  __syncthreads();
  #pragma unroll
  for (int i = 0; i < 8; i++) acc[i] = (float4v){0.f,0.f,0.f,0.f};
  gemm_t<2,4,false,false>(Xs, Xs, Bh, Bh, acc, row0, col0, gma, q);
  __syncthreads();
  emit_t<2,4>(acc, Xs, SP, row0, col0, gma, q);              // Xs = T^T
  __syncthreads();
  #pragma unroll
  for (int i = 0; i < 8; i++) acc[i] = (float4v){0.f,0.f,0.f,0.f};
  gemm_t<2,4,false,false>(Xs, Xs, Bh, Bh, acc, row0, col0, gma, q);
  __syncthreads();
  emit_t<2,4>(acc, Xs, SP, row0, col0, gma, q);              // Xs = Y (true)
  __syncthreads();
  lds_store_mat<512>(S + slot, Xs, tid);
}

// ---- prefix ----
__global__ __launch_bounds__(256) void k_prefix(ushort_t* S, const float* lamp){
  int blk = blockIdx.x;
  int chain = blk >> 4, slab = blk & 15;
  int tid = threadIdx.x;
  size_t off = (size_t)slab*1024 + tid*4;
  float lam = lamp[0];
  float a0=0.f, a1=0.f, a2=0.f, a3=0.f;
  size_t addr = (size_t)chain*16384 + off;
  const size_t step = (size_t)64*16384;
  ushort4 nxt = *(const ushort4*)&S[addr];
  for (int t = 0; t < DT; t++){
    ushort4 u = nxt;
    if (t < DT-1) nxt = *(const ushort4*)&S[addr + step];
    a0 = lam*a0 + bf2f(u.x); a1 = lam*a1 + bf2f(u.y);
    a2 = lam*a2 + bf2f(u.z); a3 = lam*a3 + bf2f(u.w);
    uint2 o; o.x = f2bfpk(a0, a1); o.y = f2bfpk(a2, a3);
    *(uint2*)&S[addr] = o;
    addr += step;
  }
}

// ---- conjmid (512 thr): S <- (1-l) M S M^T + c_t I ----
__global__ __launch_bounds__(512,4) void k_conjmid(ushort_t* S, const ushort_t* Mh,
                                                   const float* lamp){
  __shared__ ushort_t Bh[128*SP], Zs[128*SP];
  int blk = blockIdx.x;
  int t = blk >> 6, ri = blk & 1;
  size_t slot = (size_t)blk * 16384;
  int tid = threadIdx.x;
  int w = tid >> 6, lane = tid & 63, gma = lane & 15, q = lane >> 4;
  int row0 = 32*(w >> 1), col0 = 64*(w & 1);
  lds_load_mat<512>(Bh, Mh + (size_t)t*16384, tid);
  lds_load_mat<512>(Zs, S + slot, tid);
  __syncthreads();
  float lam = lamp[0];
  float oml = 1.f - lam;
  float ct = (ri == 0) ? (powf(lam, (float)(t+1)) / 128.f) : 0.f;
  float4v acc[8];
  #pragma unroll
  for (int i = 0; i < 8; i++) acc[i] = (float4v){0.f,0.f,0.f,0.f};
  gemm_t<2,4,false,false>(Zs, Zs, Bh, Bh, acc, row0, col0, gma, q);
  __syncthreads();
  emit_t<2,4>(acc, Zs, SP, row0, col0, gma, q);
  __syncthreads();
  #pragma unroll
  for (int i = 0; i < 8; i++) acc[i] = (float4v){0.f,0.f,0.f,0.f};
  gemm_t<2,4,false,false>(Zs, Zs, Bh, Bh, acc, row0, col0, gma, q);
  __syncthreads();
  #pragma unroll
  for (int R = 0; R < 2; R++)
    #pragma unroll
    for (int C = 0; C < 4; C++){
      int c = col0 + 16*C + gma, r0 = row0 + 16*R + 4*q;
      float v0 = oml*acc[R*4+C][0] + ((c == r0+0) ? ct : 0.f);
      float v1 = oml*acc[R*4+C][1] + ((c == r0+1) ? ct : 0.f);
      float v2 = oml*acc[R*4+C][2] + ((c == r0+2) ? ct : 0.f);
      float v3 = oml*acc[R*4+C][3] + ((c == r0+3) ? ct : 0.f);
      uint2 o; o.x = f2bfpk(v0, v1); o.y = f2bfpk(v2, v3);
      *(uint2*)&Zs[(size_t)c*SP + r0] = o;
    }
  __syncthreads();
  lds_store_mat<512>(S + slot, Zs, tid);
}

// ---- meas (512 thr, per (tb,h)): diag-tile MFMA epilogue, 16 waves/CU ----
__global__ __launch_bounds__(512,2) void k_meas(const ushort_t* S, const ushort_t* Wh,
                                                const float* lamp, float* Probs){
  __shared__ ushort_t Vs[128*SP], Ss[128*SP];
  __shared__ float Pd[64];
  int blk = blockIdx.x;
  int tb = blk >> 1, h = blk & 1;
  int t = tb >> 5;
  int tid = threadIdx.x;
  int w = tid >> 6, lane = tid & 63, gma = lane & 15, q = lane >> 4;
  int row0 = 32*(w >> 1), col0 = 64*(w & 1);
  size_t slot_r = (size_t)(tb*2) * 16384;
  size_t wbase = (size_t)(t*2) * 16384;
  const ushort_t* Si_g = S + slot_r + 16384;
  for (int i = tid*4; i < 16384; i += 2048){
    int r = i >> 7, k = i & 127;
    size_t gsrc = wbase + ((r < 64) ? 0 : 16384) + (size_t)(64*h + (r & 63))*128 + k;
    *(ushort4*)&Vs[r*SP+k] = *(const ushort4*)&Wh[gsrc];
    *(ushort4*)&Ss[r*SP+k] = *(const ushort4*)&S[slot_r + i];
  }
  if (tid < 64) Pd[tid] = 0.f;
  __syncthreads();
  // stage1': G1^T computed (A=Sr, B=Vs) -> transposed emit = plain G1 in Ss
  {
    float4v acc[8];
    #pragma unroll
    for (int i = 0; i < 8; i++) acc[i] = (float4v){0.f,0.f,0.f,0.f};
    gemm_t<2,4,false,false>(Ss, Ss, Vs, Vs, acc, row0, col0, gma, q);
    __syncthreads();
    emit_t<2,4>(acc, Ss, SP, row0, col0, gma, q);            // Ss = G1 plain
  }
  __syncthreads();
  // stage2: diag tiles of G1 * Vs^T : wave w -> tile w (rows 16w..16w+15)
  {
    int rr = 16*w + gma;
    float4v a1 = (float4v){0.f,0.f,0.f,0.f};
    #pragma unroll
    for (int ks = 0; ks < 4; ks++){
      int ko = ks*32 + q*8;
      bf16x8 aF = *(const bf16x8*)&Ss[rr*SP + ko];
      bf16x8 bF = *(const bf16x8*)&Vs[rr*SP + ko];
      a1 = __builtin_amdgcn_mfma_f32_16x16x32_bf16(aF, bF, a1, 0, 0, 0);
    }
    if ((gma >> 2) == q) atomicAdd(&Pd[rr & 63], a1[gma & 3]);
  }
  __syncthreads();
  // cross stage: D^T = Si * Wi^T (A = Si global rows, B = Wi = Vs rows 64+)
  {
    int wa = w >> 1, cb = w & 1;
    float4v a2[4];
    #pragma unroll
    for (int i = 0; i < 4; i++) a2[i] = (float4v){0.f,0.f,0.f,0.f};
    for (int ks = 0; ks < 4; ks++){
      int ko = ks*32 + q*8;
      bf16x8 aF[2], bF[2];
      #pragma unroll
      for (int R = 0; R < 2; R++){
        int row = 32*wa + 16*R + gma;
        aF[R] = *(const bf16x8*)&Si_g[(size_t)row*128 + ko];
      }
      #pragma unroll
      for (int C = 0; C < 2; C++){
        int row = 64 + 32*cb + 16*C + gma;
        bF[C] = *(const bf16x8*)&Vs[row*SP + ko];
      }
      #pragma unroll
      for (int R = 0; R < 2; R++)
        #pragma unroll
        for (int C = 0; C < 2; C++)
          a2[R*2+C] = __builtin_amdgcn_mfma_f32_16x16x32_bf16(aF[R], bF[C], a2[R*2+C], 0, 0, 0);
    }
    // emit transposed -> Ss rows 0..63 hold D plain (D = Wi*Si^T)
    #pragma unroll
    for (int R = 0; R < 2; R++)
      #pragma unroll
      for (int C = 0; C < 2; C++){
        int c = 32*cb + 16*C + gma, r0 = 32*wa + 16*R + 4*q;
        uint2 o;
        o.x = f2bfpk(a2[R*2+C][0], a2[R*2+C][1]);
        o.y = f2bfpk(a2[R*2+C][2], a2[R*2+C][3]);
        *(uint2*)&Ss[(size_t)c*SP + r0] = o;
      }
  }
  __syncthreads();
  // stage2c: diag tiles of D * Wr^T : waves 0..3 -> tile w (rows 16w..16w+15)
  if (w < 4){
    int rr = 16*w + gma;
    float4v a1 = (float4v){0.f,0.f,0.f,0.f};
    #pragma unroll
    for (int ks = 0; ks < 4; ks++){
      int ko = ks*32 + q*8;
      bf16x8 aF = *(const bf16x8*)&Ss[rr*SP + ko];
      bf16x8 bF = *(const bf16x8*)&Vs[rr*SP + ko];   // Wr rows 0..63
      a1 = __builtin_amdgcn_mfma_f32_16x16x32_bf16(aF, bF, a1, 0, 0, 0);
    }
    if ((gma >> 2) == q) atomicAdd(&Pd[rr], -2.f*a1[gma & 3]);
  }
  __syncthreads();
  if (tid < 64){
    float lam = lamp[0];
    float ct = powf(lam, (float)(t+1)) / 128.f;
    Probs[(size_t)tb*DD + 64*h + tid] = (1.f - lam)*Pd[tid] + ct;
  }
}

// ---- head ----
__global__ __launch_bounds__(64) void k_head(const float* Probs, const float* W1, const float* b1,
                        const float* W2, const float* b2, float* out)
{
  __shared__ float ps[DD];
  __shared__ float hid[64];
  __shared__ float ov[4];
  int tb = blockIdx.x;
  int tid = threadIdx.x;
  ps[tid] = Probs[(size_t)tb*DD + tid];
  ps[tid+64] = Probs[(size_t)tb*DD + 64 + tid];
  __syncthreads();
  float acc = b1[tid];
  for (int dd = 0; dd < DD; dd++) acc += ps[dd]*W1[dd*64 + tid];
  hid[tid] = fmaxf(acc, 0.f);
  __syncthreads();
  if (tid < 4){
    float o = b2[tid];
    for (int j = 0; j < 64; j++) o += hid[j]*W2[j*4 + tid];
    ov[tid] = tanhf(o);
  }
  __syncthreads();
  if (tid == 0){
    float m = fmaxf(fmaxf(ov[0],ov[1]), fmaxf(ov[2],ov[3]));
    float lse = logf(expf(ov[0]-m)+expf(ov[1]-m)+expf(ov[2]-m)+expf(ov[3]-m));
    int t = tb >> 5, b = tb & 31;
    float* o = out + ((size_t)(b*DT + t))*4;
    o[0] = ov[0]-m-lse; o[1] = ov[1]-m-lse;
    o[2] = ov[2]-m-lse; o[3] = ov[3]-m-lse;
  }
}

extern "C" void kernel_launch(void* const* d_in, const int* in_sizes, int n_in,
                              void* d_out, int out_size, void* d_ws, size_t ws_size,
                              hipStream_t stream)
{
  const float* x0    = (const float*)d_in[0];
  const float* x1    = (const float*)d_in[1];
  const float* x2    = (const float*)d_in[2];
  const float* smask = (const float*)d_in[3];
  const float* Wp0   = (const float*)d_in[4];
  const float* bp0   = (const float*)d_in[5];
  const float* Wp1   = (const float*)d_in[6];
  const float* bp1   = (const float*)d_in[7];
  const float* Wp2   = (const float*)d_in[8];
  const float* bp2   = (const float*)d_in[9];
  const float* freq  = (const float*)d_in[10];
  const float* phem  = (const float*)d_in[11];
  const float* Ux    = (const float*)d_in[12];
  const float* Uh    = (const float*)d_in[13];
  const float* lamp  = (const float*)d_in[14];
  const float* kr    = (const float*)d_in[15];
  const float* ki    = (const float*)d_in[16];
  const float* W1    = (const float*)d_in[17];
  const float* b1    = (const float*)d_in[18];
  const float* W2    = (const float*)d_in[19];
  const float* b2    = (const float*)d_in[20];

  char* ws = (char*)d_ws;
  auto alignup = [](size_t x){ return (x + 255) & ~(size_t)255; };
  size_t off = 0;
  ushort_t* S   = (ushort_t*)(ws + off); off = alignup(off + (size_t)3840*16384*sizeof(ushort_t));
  float* Qbuf   = (float*)(ws + off);    off = alignup(off + (size_t)6*BT*DD*sizeof(float));
  float* Wgt    = (float*)(ws + off);    off = alignup(off + (size_t)BT*3*sizeof(float));
  float* Vr     = (float*)(ws + off);    off = alignup(off + (size_t)DD*DD*sizeof(float));
  float* Vi     = (float*)(ws + off);    off = alignup(off + (size_t)DD*DD*sizeof(float));
  ushort_t* UxTh = (ushort_t*)(ws + off); off = alignup(off + (size_t)DD*DD*sizeof(ushort_t));
  ushort_t* UxTl = (ushort_t*)(ws + off); off = alignup(off + (size_t)DD*DD*sizeof(ushort_t));
  float* Probs  = (float*)(ws + off);    off = alignup(off + (size_t)BT*DD*sizeof(float));
  ushort_t* PpH = (ushort_t*)(ws + off); off = alignup(off + (size_t)6*16384*sizeof(ushort_t));
  ushort_t* PpL = (ushort_t*)(ws + off); off = alignup(off + (size_t)6*16384*sizeof(ushort_t));
  ushort_t* PTh = (ushort_t*)(ws + off); off = alignup(off + (size_t)6*16384*sizeof(ushort_t));
  ushort_t* PTl = (ushort_t*)(ws + off); off = alignup(off + (size_t)6*16384*sizeof(ushort_t));
  ushort_t* Mh  = (ushort_t*)(ws + off); off = alignup(off + (size_t)60*16384*sizeof(ushort_t));
  ushort_t* Wmh = (ushort_t*)(ws + off); off = alignup(off + (size_t)120*16384*sizeof(ushort_t));
  ushort_t* GTh = (ushort_t*)(ws + off); off = alignup(off + (size_t)60*16384*sizeof(ushort_t));
  ushort_t* GTl = (ushort_t*)(ws + off); off = alignup(off + (size_t)60*16384*sizeof(ushort_t));
  (void)ws_size; (void)in_sizes; (void)n_in; (void)out_size;

  k_small<<<384, 128, 0, stream>>>(Ux, Uh, kr, ki, UxTh, UxTl, Vr, Vi, PpH, PpL, PTh, PTl);
  k_prep<<<BT, 128, 0, stream>>>(x0, x1, x2, smask, Wp0, bp0, Wp1, bp1, Wp2, bp2, freq, phem, Ux, Qbuf, Wgt);
  k_pow2<<<1, 256, 0, stream>>>(PpH, PpL, PTh, PTl);
  k_gchain<<<60, 256, 0, stream>>>(PpH, PpL, PTh, PTl, GTh, GTl);
  k_precompMW<<<180, 256, 0, stream>>>(GTh, GTl, UxTh, UxTl, Vr, Vi, Mh, Wmh);
  k_conjL1<<<3840, 512, 0, stream>>>(S, GTh, Qbuf, Wgt);
  k_prefix<<<1024, 256, 0, stream>>>(S, lamp);
  k_conjmid<<<3840, 512, 0, stream>>>(S, Mh, lamp);
  k_prefix<<<1024, 256, 0, stream>>>(S, lamp);
  k_meas<<<3840, 512, 0, stream>>>(S, Wmh, lamp, Probs);
  k_head<<<BT, 64, 0, stream>>>(Probs, W1, b1, W2, b2, (float*)d_out);
}

// Round 10
// 468.020 us; speedup vs baseline: 1.4082x; 1.2042x over previous
//
#include <hip/hip_runtime.h>

// QMN B=32,T=60,D=128. Round 10: symmetry fold.
// Sr symmetric / Si antisymmetric at EVERY stage -> store C = Sr + Si (one
// general 128x128 per (t,b) instead of two): halves S buffer, S traffic and
// conj GEMM block count. Conj chains (traced symbolically) already handle
// general matrices: final = G^T C G / M C M^T. Measurement: w^T Sr w = w^T C^T w
// (quad forms C^T-insensitive); 2 wi Si wr = wi C wr - wi C^T wr = E4-E3 from
// diag tiles of the single staged Vs*C^T -> cross-GEMM eliminated.
// conjL1 X-build: raw q on A side, weighted combo (w*(qr+qi), w*(qi-qr)) on B.

#define DB 32
#define DT 60
#define DD 128
#define BT (DB*DT)
#define SP 136
#define BSTR 36

typedef unsigned short ushort_t;
typedef __attribute__((ext_vector_type(8))) __bf16 bf16x8;
typedef __attribute__((ext_vector_type(4))) float  float4v;

__device__ __forceinline__ float bf2f(ushort_t u){
  union { unsigned int i; float f; } x; x.i = ((unsigned int)u) << 16; return x.f;
}
__device__ __forceinline__ ushort_t f2bf(float f){
  union { float f; unsigned int i; } x; x.f = f;
  unsigned int lsb = (x.i >> 16) & 1u;
  return (ushort_t)((x.i + 0x7FFFu + lsb) >> 16);
}
__device__ __forceinline__ unsigned int f2bfpk(float a, float b){
#if defined(__gfx950__) && __has_builtin(__builtin_amdgcn_cvt_pk_bf16_f32)
  auto v = __builtin_amdgcn_cvt_pk_bf16_f32(a, b);
  unsigned int r; __builtin_memcpy(&r, &v, 4); return r;
#else
  return (unsigned int)f2bf(a) | ((unsigned int)f2bf(b) << 16);
#endif
}
__device__ __forceinline__ void split2(float v, ushort_t& h, ushort_t& l){
  h = f2bf(v); l = f2bf(v - bf2f(h));
}

// D[m][n] = sum_k A[m][k]*B[n][k]
template<int RT, int CT, bool ALO, bool BLO>
__device__ __forceinline__ void gemm_t(const ushort_t* Ah, const ushort_t* Al,
                                       const ushort_t* Bh, const ushort_t* Bl,
                                       float4v* acc, int row0, int col0, int gma, int q)
{
  for (int ks = 0; ks < 4; ks++){
    int ko = ks*32 + q*8;
    bf16x8 aF[RT], aL[RT], bF[CT], bL[CT];
    #pragma unroll
    for (int R = 0; R < RT; R++){
      int row = row0 + 16*R + gma;
      aF[R] = *(const bf16x8*)&Ah[row*SP + ko];
      if (ALO) aL[R] = *(const bf16x8*)&Al[row*SP + ko];
    }
    #pragma unroll
    for (int C = 0; C < CT; C++){
      int row = col0 + 16*C + gma;
      bF[C] = *(const bf16x8*)&Bh[row*SP + ko];
      if (BLO) bL[C] = *(const bf16x8*)&Bl[row*SP + ko];
    }
    #pragma unroll
    for (int R = 0; R < RT; R++)
      #pragma unroll
      for (int C = 0; C < CT; C++){
        float4v c = acc[R*CT+C];
        c = __builtin_amdgcn_mfma_f32_16x16x32_bf16(aF[R], bF[C], c, 0, 0, 0);
        if (BLO) c = __builtin_amdgcn_mfma_f32_16x16x32_bf16(aF[R], bL[C], c, 0, 0, 0);
        if (ALO) c = __builtin_amdgcn_mfma_f32_16x16x32_bf16(aL[R], bF[C], c, 0, 0, 0);
        acc[R*CT+C] = c;
      }
  }
}

// transposed store computed(m,n) -> dst[n*stride + m]
template<int RT, int CT>
__device__ __forceinline__ void emit_t(const float4v* acc, ushort_t* dst, int stride,
                                       int row0, int col0, int gma, int q){
  #pragma unroll
  for (int R = 0; R < RT; R++)
    #pragma unroll
    for (int C = 0; C < CT; C++){
      int c = col0 + 16*C + gma, r0 = row0 + 16*R + 4*q;
      uint2 o;
      o.x = f2bfpk(acc[R*CT+C][0], acc[R*CT+C][1]);
      o.y = f2bfpk(acc[R*CT+C][2], acc[R*CT+C][3]);
      *(uint2*)&dst[(size_t)c*stride + r0] = o;
    }
}
__device__ __forceinline__ void emit_split44(const float4v* acc, ushort_t* dh, ushort_t* dl, int stride,
                                             int row0, int col0, int gma, int q){
  #pragma unroll
  for (int R = 0; R < 4; R++)
    #pragma unroll
    for (int C = 0; C < 4; C++){
      int c = col0 + 16*C + gma, r0 = row0 + 16*R + 4*q;
      ushort4 hh, ll;
      split2(acc[R*4+C][0], hh.x, ll.x); split2(acc[R*4+C][1], hh.y, ll.y);
      split2(acc[R*4+C][2], hh.z, ll.z); split2(acc[R*4+C][3], hh.w, ll.w);
      *(ushort4*)&dh[(size_t)c*stride + r0] = hh;
      *(ushort4*)&dl[(size_t)c*stride + r0] = ll;
    }
}
__device__ __forceinline__ void emit_plain_lds44(const float4v* acc, ushort_t* dh, ushort_t* dl,
                                                 int row0, int col0, int gma, int q){
  #pragma unroll
  for (int R = 0; R < 4; R++)
    #pragma unroll
    for (int C = 0; C < 4; C++){
      int c = col0 + 16*C + gma, r0 = row0 + 16*R + 4*q;
      #pragma unroll
      for (int j = 0; j < 4; j++){
        ushort_t h, l; split2(acc[R*4+C][j], h, l);
        dh[(size_t)(r0+j)*SP + c] = h;
        dl[(size_t)(r0+j)*SP + c] = l;
      }
    }
}
template<int NT>
__device__ __forceinline__ void lds_load_mat(ushort_t* dst, const ushort_t* src, int tid){
  for (int i = tid*4; i < 16384; i += NT*4){
    int r = i >> 7, k = i & 127;
    *(ushort4*)&dst[r*SP + k] = *(const ushort4*)&src[i];
  }
}
template<int NT>
__device__ __forceinline__ void lds_store_mat(ushort_t* dst, const ushort_t* src, int tid){
  for (int i = tid*4; i < 16384; i += NT*4){
    int r = i >> 7, k = i & 127;
    *(ushort4*)&dst[i] = *(const ushort4*)&src[r*SP + k];
  }
}

// ---- small: prepU | normv | initG ----
__global__ void k_small(const float* Ux, const float* Uh, const float* kr, const float* ki,
                        ushort_t* UxTh, ushort_t* UxTl, float* Vr, float* Vi,
                        ushort_t* PpH, ushort_t* PpL, ushort_t* PTh, ushort_t* PTl){
  int blk = blockIdx.x, d = threadIdx.x;
  if (blk < 128){
    int i = blk;
    float v = Ux[i*DD + d];
    ushort_t h, l; split2(v, h, l);
    UxTh[d*DD + i] = h; UxTl[d*DD + i] = l;
  } else if (blk < 256){
    __shared__ float red[DD];
    int k = blk - 128;
    float r = kr[k*DD+d], im = ki[k*DD+d];
    red[d] = r*r + im*im;
    __syncthreads();
    for (int s = 64; s > 0; s >>= 1){ if (d < s) red[d] += red[d+s]; __syncthreads(); }
    float nrm = fmaxf(sqrtf(red[0]), 1e-12f);
    Vr[k*DD+d] = r/nrm; Vi[k*DD+d] = im/nrm;
  } else {
    int i = blk - 256;
    float v = Uh[i*DD + d];
    ushort_t h, l; split2(v, h, l);
    PpH[i*DD + d] = h;  PpL[i*DD + d] = l;
    PTh[d*DD + i] = h;  PTl[d*DD + i] = l;
  }
}

// ---- pow2: G^{2^s}, s=1..5 ----
__global__ __launch_bounds__(256,1) void k_pow2(ushort_t* PpH, ushort_t* PpL,
                                                ushort_t* PTh, ushort_t* PTl){
  __shared__ ushort_t Ah[128*SP], Al[128*SP], Bh[128*SP], Bl[128*SP];
  int tid = threadIdx.x;
  int w = tid >> 6, lane = tid & 63, gma = lane & 15, q = lane >> 4;
  int row0 = 64*(w >> 1), col0 = 64*(w & 1);
  lds_load_mat<256>(Ah, PpH, tid);
  lds_load_mat<256>(Al, PpL, tid);
  lds_load_mat<256>(Bh, PTh, tid);
  lds_load_mat<256>(Bl, PTl, tid);
  __syncthreads();
  for (int s = 1; s <= 5; s++){
    float4v acc[16];
    #pragma unroll
    for (int i = 0; i < 16; i++) acc[i] = (float4v){0.f,0.f,0.f,0.f};
    gemm_t<4,4,true,true>(Ah, Al, Bh, Bl, acc, row0, col0, gma, q);
    __syncthreads();
    emit_plain_lds44(acc, Ah, Al, row0, col0, gma, q);
    emit_split44(acc, Bh, Bl, SP, row0, col0, gma, q);
    size_t slot = (size_t)s * 16384;
    emit_split44(acc, PTh + slot, PTl + slot, 128, row0, col0, gma, q);
    #pragma unroll
    for (int R = 0; R < 4; R++)
      #pragma unroll
      for (int C = 0; C < 4; C++){
        int c = col0 + 16*C + gma, r0 = row0 + 16*R + 4*q;
        #pragma unroll
        for (int j = 0; j < 4; j++){
          ushort_t h, l; split2(acc[R*4+C][j], h, l);
          PpH[slot + (size_t)(r0+j)*128 + c] = h;
          PpL[slot + (size_t)(r0+j)*128 + c] = l;
        }
      }
    __syncthreads();
  }
}

// ---- gchain ----
__global__ __launch_bounds__(256,1) void k_gchain(const ushort_t* PpH, const ushort_t* PpL,
                                                  const ushort_t* PTh, const ushort_t* PTl,
                                                  ushort_t* GTh, ushort_t* GTl){
  __shared__ ushort_t Ah[128*SP], Al[128*SP], Bh[128*SP], Bl[128*SP];
  int t = blockIdx.x;
  int tid = threadIdx.x;
  int w = tid >> 6, lane = tid & 63, gma = lane & 15, q = lane >> 4;
  int row0 = 64*(w >> 1), col0 = 64*(w & 1);
  size_t gslot = (size_t)t * 16384;
  if (t == 0){
    for (int i = tid*4; i < 16384; i += 1024){
      int r = i >> 7, k = i & 127;
      ushort4 zz; zz.x = zz.y = zz.z = zz.w = 0;
      *(ushort4*)&GTl[gslot + i] = zz;
      ushort4 oh;
      oh.x = (r == (k+0)) ? (ushort_t)0x3F80 : (ushort_t)0;
      oh.y = (r == (k+1)) ? (ushort_t)0x3F80 : (ushort_t)0;
      oh.z = (r == (k+2)) ? (ushort_t)0x3F80 : (ushort_t)0;
      oh.w = (r == (k+3)) ? (ushort_t)0x3F80 : (ushort_t)0;
      *(ushort4*)&GTh[gslot + i] = oh;
    }
    return;
  }
  int b0 = __ffs(t) - 1;
  int rem = t & ~(1 << b0);
  if (rem == 0){
    size_t ps = (size_t)b0 * 16384;
    for (int i = tid*4; i < 16384; i += 1024){
      *(ushort4*)&GTh[gslot + i] = *(const ushort4*)&PTh[ps + i];
      *(ushort4*)&GTl[gslot + i] = *(const ushort4*)&PTl[ps + i];
    }
    return;
  }
  lds_load_mat<256>(Ah, PpH + (size_t)b0*16384, tid);
  lds_load_mat<256>(Al, PpL + (size_t)b0*16384, tid);
  while (rem){
    int k = __ffs(rem) - 1;
    rem &= ~(1 << k);
    lds_load_mat<256>(Bh, PTh + (size_t)k*16384, tid);
    lds_load_mat<256>(Bl, PTl + (size_t)k*16384, tid);
    __syncthreads();
    float4v acc[16];
    #pragma unroll
    for (int i = 0; i < 16; i++) acc[i] = (float4v){0.f,0.f,0.f,0.f};
    gemm_t<4,4,true,true>(Ah, Al, Bh, Bl, acc, row0, col0, gma, q);
    __syncthreads();
    if (rem){
      emit_plain_lds44(acc, Ah, Al, row0, col0, gma, q);
      __syncthreads();
    } else {
      emit_split44(acc, GTh + gslot, GTl + gslot, 128, row0, col0, gma, q);
    }
  }
}

// ---- precompMW ----
__global__ __launch_bounds__(256,1) void k_precompMW(const ushort_t* GTh, const ushort_t* GTl,
                                                     const ushort_t* UxTh, const ushort_t* UxTl,
                                                     const float* Vr, const float* Vi,
                                                     ushort_t* Mh, ushort_t* Wh){
  __shared__ ushort_t Bh[128*SP], Bl[128*SP], Ah[128*SP], Al[128*SP];
  int blk = blockIdx.x;
  int tid = threadIdx.x;
  int w = tid >> 6, lane = tid & 63, gma = lane & 15, q = lane >> 4;
  int row0 = 64*(w >> 1), col0 = 64*(w & 1);
  if (blk < 60){
    int t = blk;
    lds_load_mat<256>(Bh, GTh + (size_t)t*16384, tid);
    lds_load_mat<256>(Bl, GTl + (size_t)t*16384, tid);
    lds_load_mat<256>(Ah, UxTh, tid);
    lds_load_mat<256>(Al, UxTl, tid);
    __syncthreads();
    float4v acc[16];
    #pragma unroll
    for (int i = 0; i < 16; i++) acc[i] = (float4v){0.f,0.f,0.f,0.f};
    gemm_t<4,4,true,true>(Ah, Al, Bh, Bl, acc, row0, col0, gma, q);
    __syncthreads();
    emit_split44(acc, Ah, Al, SP, row0, col0, gma, q);
    __syncthreads();
    #pragma unroll
    for (int i = 0; i < 16; i++) acc[i] = (float4v){0.f,0.f,0.f,0.f};
    gemm_t<4,4,true,true>(Bh, Bl, Ah, Al, acc, row0, col0, gma, q);
    #pragma unroll
    for (int R = 0; R < 4; R++)
      #pragma unroll
      for (int C = 0; C < 4; C++){
        int c = col0 + 16*C + gma, r0 = row0 + 16*R + 4*q;
        uint2 o;
        o.x = f2bfpk(acc[R*4+C][0], acc[R*4+C][1]);
        o.y = f2bfpk(acc[R*4+C][2], acc[R*4+C][3]);
        *(uint2*)&Mh[(size_t)t*16384 + c*128 + r0] = o;
      }
  } else {
    int bx = blk - 60;
    int t = bx >> 1, which = bx & 1;
    lds_load_mat<256>(Ah, GTh + (size_t)t*16384, tid);
    lds_load_mat<256>(Al, GTl + (size_t)t*16384, tid);
    const float* V = which ? Vi : Vr;
    for (int i = tid; i < 16384; i += 256){
      int r = i >> 7, k = i & 127;
      ushort_t h, l; split2(V[i], h, l);
      Bh[r*SP + k] = h; Bl[r*SP + k] = l;
    }
    __syncthreads();
    float4v acc[16];
    #pragma unroll
    for (int i = 0; i < 16; i++) acc[i] = (float4v){0.f,0.f,0.f,0.f};
    gemm_t<4,4,true,true>(Ah, Al, Bh, Bl, acc, row0, col0, gma, q);
    #pragma unroll
    for (int R = 0; R < 4; R++)
      #pragma unroll
      for (int C = 0; C < 4; C++){
        int c = col0 + 16*C + gma, r0 = row0 + 16*R + 4*q;
        uint2 o;
        o.x = f2bfpk(acc[R*4+C][0], acc[R*4+C][1]);
        o.y = f2bfpk(acc[R*4+C][2], acc[R*4+C][3]);
        *(uint2*)&Wh[(size_t)bx*16384 + c*128 + r0] = o;
      }
  }
}

// ---- prep (fused qtrans) ----
__global__ __launch_bounds__(128) void k_prep(
    const float* x0, const float* x1, const float* x2, const float* smask,
    const float* Wp0, const float* bp0, const float* Wp1, const float* bp1,
    const float* Wp2, const float* bp2, const float* freq, const float* phem,
    const float* Ux, float* Q, float* Wgt)
{
  __shared__ float xs[768+74+35];
  __shared__ float red[DD];
  __shared__ float nrm3[3];
  __shared__ float ps[6][DD];
  int bt = blockIdx.x; int t = bt % DT;
  int d = threadIdx.x;
  const float* r0 = x0 + (size_t)bt*768;
  for (int k = d; k < 768; k += DD) xs[k] = r0[k];
  const float* r1 = x1 + (size_t)bt*74;
  if (d < 74) xs[768+d] = r1[d];
  const float* r2 = x2 + (size_t)bt*35;
  if (d < 35) xs[768+74+d] = r2[d];
  __syncthreads();
  float rep[3];
  { float acc = bp0[d]; for (int k = 0; k < 768; k++) acc += xs[k]*Wp0[k*DD+d]; rep[0] = fmaxf(acc, 0.f); }
  { float acc = bp1[d]; for (int k = 0; k < 74; k++) acc += xs[768+k]*Wp1[k*DD+d]; rep[1] = fmaxf(acc, 0.f); }
  { float acc = bp2[d]; for (int k = 0; k < 35; k++) acc += xs[768+74+k]*Wp2[k*DD+d]; rep[2] = fmaxf(acc, 0.f); }
  for (int m = 0; m < 3; m++){
    red[d] = rep[m]*rep[m];
    __syncthreads();
    for (int s = 64; s > 0; s >>= 1){ if (d < s) red[d] += red[d+s]; __syncthreads(); }
    if (d == 0) nrm3[m] = sqrtf(red[0]);
    __syncthreads();
  }
  float n0 = nrm3[0], n1 = nrm3[1], n2 = nrm3[2];
  float mx = fmaxf(n0, fmaxf(n1, n2));
  float e0 = expf(n0-mx), e1 = expf(n1-mx), e2 = expf(n2-mx);
  float einv = 1.f/(e0+e1+e2);
  if (d < 3) Wgt[bt*3+d] = (d==0?e0:(d==1?e1:e2))*einv;
  float s0 = smask[bt*2], s1 = smask[bt*2+1];
  int id = (s1 > s0) ? 1 : 0;
  float ph = (float)t * freq[id*DD+d] + phem[id*DD+d];
  float cp = cosf(ph), sp = sinf(ph);
  for (int m = 0; m < 3; m++){
    float a = rep[m] / fmaxf(nrm3[m], 1e-12f);
    ps[m][d]   = a*cp;
    ps[3+m][d] = a*sp;
  }
  __syncthreads();
  float qv[6] = {0.f,0.f,0.f,0.f,0.f,0.f};
  const float* uxr = Ux + (size_t)d*DD;
  for (int p = 0; p < DD; p++){
    float u = uxr[p];
    #pragma unroll
    for (int j = 0; j < 6; j++) qv[j] += u * ps[j][p];
  }
  #pragma unroll
  for (int j = 0; j < 6; j++)
    Q[((size_t)(j*BT) + bt)*DD + d] = qv[j];
}

// ---- conjL1 (512 thr, per (t,b)): C = Xr+Xi via rank-6 MFMA, S <- G^T C G ----
__global__ __launch_bounds__(512,4) void k_conjL1(ushort_t* S, const ushort_t* GTh,
                                                  const float* Q, const float* Wgt){
  __shared__ ushort_t Bh[128*SP], Xs[128*SP];
  __shared__ float wl[3];
  ushort_t* Bstage = Xs;
  int blk = blockIdx.x;            // t*DB+b
  int t = blk >> 5, b = blk & 31;
  int bt_in = b*DT + t;
  size_t slot = (size_t)blk * 16384;
  int tid = threadIdx.x;
  int w = tid >> 6, lane = tid & 63, gma = lane & 15, q = lane >> 4;
  int row0 = 32*(w >> 1), col0 = 64*(w & 1);
  lds_load_mat<512>(Bh, GTh + (size_t)t*16384, tid);
  for (int i = tid*4; i < 128*BSTR; i += 2048){
    ushort4 z; z.x = z.y = z.z = z.w = 0;
    *(ushort4*)&Bstage[i] = z;
  }
  if (tid < 3) wl[tid] = Wgt[bt_in*3 + tid];
  __syncthreads();
  for (int l = tid; l < 6*DD; l += 512){
    int j = l >> 7, r = l & 127;
    Bstage[r*BSTR + j] = f2bf(Q[((size_t)(j*BT) + bt_in)*DD + r]);
  }
  __syncthreads();
  float4v acc[8];
  {
    // D[r][c] = C[c][r]: A = raw q rows, B[c][j<3] = w_j(qr_j[c]+qi_j[c]),
    // B[c][3+j] = w_j(qi_j[c]-qr_j[c]); transposed emit -> Xs = C row-major.
    float w0 = wl[0], w1 = wl[1], w2 = wl[2];
    bf16x8 aF[2], bF[4];
    #pragma unroll
    for (int R = 0; R < 2; R++){
      int r = row0 + 16*R + gma;
      aF[R] = *(const bf16x8*)&Bstage[r*BSTR + q*8];
    }
    #pragma unroll
    for (int C = 0; C < 4; C++){
      int c = col0 + 16*C + gma;
      bf16x8 braw = *(const bf16x8*)&Bstage[c*BSTR + q*8];
      const ushort_t* bu = (const ushort_t*)&braw;
      union { ushort_t u[8]; bf16x8 v; } au;
      #pragma unroll
      for (int j = 0; j < 8; j++) au.u[j] = 0;
      if (q == 0){
        float b0 = bf2f(bu[0]), b1 = bf2f(bu[1]), b2 = bf2f(bu[2]);
        float b3 = bf2f(bu[3]), b4 = bf2f(bu[4]), b5 = bf2f(bu[5]);
        au.u[0] = f2bf(w0*(b0+b3)); au.u[1] = f2bf(w1*(b1+b4)); au.u[2] = f2bf(w2*(b2+b5));
        au.u[3] = f2bf(w0*(b3-b0)); au.u[4] = f2bf(w1*(b4-b1)); au.u[5] = f2bf(w2*(b5-b2));
      }
      bF[C] = au.v;
    }
    #pragma unroll
    for (int i = 0; i < 8; i++) acc[i] = (float4v){0.f,0.f,0.f,0.f};
    #pragma unroll
    for (int R = 0; R < 2; R++)
      #pragma unroll
      for (int C = 0; C < 4; C++)
        acc[R*4+C] = __builtin_amdgcn_mfma_f32_16x16x32_bf16(aF[R], bF[C], acc[R*4+C], 0, 0, 0);
  }
  __syncthreads();
  emit_t<2,4>(acc, Xs, SP, row0, col0, gma, q);              // Xs = C (true)
  __syncthreads();
  #pragma unroll
  for (int i = 0; i < 8; i++) acc[i] = (float4v){0.f,0.f,0.f,0.f};
  gemm_t<2,4,false,false>(Xs, Xs, Bh, Bh, acc, row0, col0, gma, q);
  __syncthreads();
  emit_t<2,4>(acc, Xs, SP, row0, col0, gma, q);              // Xs = G^T C^T
  __syncthreads();
  #pragma unroll
  for (int i = 0; i < 8; i++) acc[i] = (float4v){0.f,0.f,0.f,0.f};
  gemm_t<2,4,false,false>(Xs, Xs, Bh, Bh, acc, row0, col0, gma, q);
  __syncthreads();
  emit_t<2,4>(acc, Xs, SP, row0, col0, gma, q);              // Xs = G^T C G
  __syncthreads();
  lds_store_mat<512>(S + slot, Xs, tid);
}

// ---- prefix: Z_t = lam*Z_{t-1} + Y_t (32 chains) ----
__global__ __launch_bounds__(256) void k_prefix(ushort_t* S, const float* lamp){
  int blk = blockIdx.x;            // 512 = 32 chains x 16 slabs
  int chain = blk >> 4, slab = blk & 15;
  int tid = threadIdx.x;
  size_t off = (size_t)slab*1024 + tid*4;
  float lam = lamp[0];
  float a0=0.f, a1=0.f, a2=0.f, a3=0.f;
  size_t addr = (size_t)chain*16384 + off;
  const size_t step = (size_t)32*16384;
  ushort4 nxt = *(const ushort4*)&S[addr];
  for (int t = 0; t < DT; t++){
    ushort4 u = nxt;
    if (t < DT-1) nxt = *(const ushort4*)&S[addr + step];
    a0 = lam*a0 + bf2f(u.x); a1 = lam*a1 + bf2f(u.y);
    a2 = lam*a2 + bf2f(u.z); a3 = lam*a3 + bf2f(u.w);
    uint2 o; o.x = f2bfpk(a0, a1); o.y = f2bfpk(a2, a3);
    *(uint2*)&S[addr] = o;
    addr += step;
  }
}

// ---- conjmid (512 thr, per (t,b)): S <- (1-l) M S M^T + c_t I ----
__global__ __launch_bounds__(512,4) void k_conjmid(ushort_t* S, const ushort_t* Mh,
                                                   const float* lamp){
  __shared__ ushort_t Bh[128*SP], Zs[128*SP];
  int blk = blockIdx.x;
  int t = blk >> 5;
  size_t slot = (size_t)blk * 16384;
  int tid = threadIdx.x;
  int w = tid >> 6, lane = tid & 63, gma = lane & 15, q = lane >> 4;
  int row0 = 32*(w >> 1), col0 = 64*(w & 1);
  lds_load_mat<512>(Bh, Mh + (size_t)t*16384, tid);
  lds_load_mat<512>(Zs, S + slot, tid);
  __syncthreads();
  float lam = lamp[0];
  float oml = 1.f - lam;
  float ct = powf(lam, (float)(t+1)) / 128.f;
  float4v acc[8];
  #pragma unroll
  for (int i = 0; i < 8; i++) acc[i] = (float4v){0.f,0.f,0.f,0.f};
  gemm_t<2,4,false,false>(Zs, Zs, Bh, Bh, acc, row0, col0, gma, q);
  __syncthreads();
  emit_t<2,4>(acc, Zs, SP, row0, col0, gma, q);
  __syncthreads();
  #pragma unroll
  for (int i = 0; i < 8; i++) acc[i] = (float4v){0.f,0.f,0.f,0.f};
  gemm_t<2,4,false,false>(Zs, Zs, Bh, Bh, acc, row0, col0, gma, q);
  __syncthreads();
  #pragma unroll
  for (int R = 0; R < 2; R++)
    #pragma unroll
    for (int C = 0; C < 4; C++){
      int c = col0 + 16*C + gma, r0 = row0 + 16*R + 4*q;
      float v0 = oml*acc[R*4+C][0] + ((c == r0+0) ? ct : 0.f);
      float v1 = oml*acc[R*4+C][1] + ((c == r0+1) ? ct : 0.f);
      float v2 = oml*acc[R*4+C][2] + ((c == r0+2) ? ct : 0.f);
      float v3 = oml*acc[R*4+C][3] + ((c == r0+3) ? ct : 0.f);
      uint2 o; o.x = f2bfpk(v0, v1); o.y = f2bfpk(v2, v3);
      *(uint2*)&Zs[(size_t)c*SP + r0] = o;
    }
  __syncthreads();
  lds_store_mat<512>(S + slot, Zs, tid);
}

// ---- meas (512 thr, per (tb,h)): stage1 Vs*C^T then 16 diag tiles ----
// probs_k = (1-l)*(E1 + E2 - E3 + E4) + c_t, where with Ss = Vs*C^T:
// E1=Ss[k].Vs[k], E2=Ss[64+k].Vs[64+k], E3=Ss[64+k].Vs[k], E4=Ss[k].Vs[64+k]
__global__ __launch_bounds__(512,2) void k_meas(const ushort_t* S, const ushort_t* Wh,
                                                const float* lamp, float* Probs){
  __shared__ ushort_t Vs[128*SP], Ss[128*SP];
  __shared__ float Pd[64];
  int blk = blockIdx.x;
  int tb = blk >> 1, h = blk & 1;
  int t = tb >> 5;
  int tid = threadIdx.x;
  int w = tid >> 6, lane = tid & 63, gma = lane & 15, q = lane >> 4;
  int row0 = 32*(w >> 1), col0 = 64*(w & 1);
  size_t slot = (size_t)tb * 16384;
  size_t wbase = (size_t)(t*2) * 16384;
  for (int i = tid*4; i < 16384; i += 2048){
    int r = i >> 7, k = i & 127;
    size_t gsrc = wbase + ((r < 64) ? 0 : 16384) + (size_t)(64*h + (r & 63))*128 + k;
    *(ushort4*)&Vs[r*SP+k] = *(const ushort4*)&Wh[gsrc];
    *(ushort4*)&Ss[r*SP+k] = *(const ushort4*)&S[slot + i];
  }
  if (tid < 64) Pd[tid] = 0.f;
  __syncthreads();
  {
    float4v acc[8];
    #pragma unroll
    for (int i = 0; i < 8; i++) acc[i] = (float4v){0.f,0.f,0.f,0.f};
    gemm_t<2,4,false,false>(Ss, Ss, Vs, Vs, acc, row0, col0, gma, q);
    __syncthreads();
    emit_t<2,4>(acc, Ss, SP, row0, col0, gma, q);            // Ss = Vs * C^T
  }
  __syncthreads();
  #pragma unroll
  for (int g = 0; g < 2; g++){
    int ti = 2*w + g;                  // 16 tiles over 8 waves
    int grp = ti >> 2, sub = ti & 3;
    int arow = (((grp == 1) || (grp == 2)) ? 64 : 0) + 16*sub + gma;
    int brow = (((grp == 1) || (grp == 3)) ? 64 : 0) + 16*sub + gma;
    float coef = (grp == 2) ? -1.f : 1.f;
    float4v a1 = (float4v){0.f,0.f,0.f,0.f};
    #pragma unroll
    for (int ks = 0; ks < 4; ks++){
      int ko = ks*32 + q*8;
      bf16x8 aF = *(const bf16x8*)&Ss[arow*SP + ko];
      bf16x8 bF = *(const bf16x8*)&Vs[brow*SP + ko];
      a1 = __builtin_amdgcn_mfma_f32_16x16x32_bf16(aF, bF, a1, 0, 0, 0);
    }
    if ((gma >> 2) == q) atomicAdd(&Pd[16*sub + gma], coef * a1[gma & 3]);
  }
  __syncthreads();
  if (tid < 64){
    float lam = lamp[0];
    float ct = powf(lam, (float)(t+1)) / 128.f;
    Probs[(size_t)tb*DD + 64*h + tid] = (1.f - lam)*Pd[tid] + ct;
  }
}

// ---- head ----
__global__ __launch_bounds__(64) void k_head(const float* Probs, const float* W1, const float* b1,
                        const float* W2, const float* b2, float* out)
{
  __shared__ float ps[DD];
  __shared__ float hid[64];
  __shared__ float ov[4];
  int tb = blockIdx.x;
  int tid = threadIdx.x;
  ps[tid] = Probs[(size_t)tb*DD + tid];
  ps[tid+64] = Probs[(size_t)tb*DD + 64 + tid];
  __syncthreads();
  float acc = b1[tid];
  for (int dd = 0; dd < DD; dd++) acc += ps[dd]*W1[dd*64 + tid];
  hid[tid] = fmaxf(acc, 0.f);
  __syncthreads();
  if (tid < 4){
    float o = b2[tid];
    for (int j = 0; j < 64; j++) o += hid[j]*W2[j*4 + tid];
    ov[tid] = tanhf(o);
  }
  __syncthreads();
  if (tid == 0){
    float m = fmaxf(fmaxf(ov[0],ov[1]), fmaxf(ov[2],ov[3]));
    float lse = logf(expf(ov[0]-m)+expf(ov[1]-m)+expf(ov[2]-m)+expf(ov[3]-m));
    int t = tb >> 5, b = tb & 31;
    float* o = out + ((size_t)(b*DT + t))*4;
    o[0] = ov[0]-m-lse; o[1] = ov[1]-m-lse;
    o[2] = ov[2]-m-lse; o[3] = ov[3]-m-lse;
  }
}

extern "C" void kernel_launch(void* const* d_in, const int* in_sizes, int n_in,
                              void* d_out, int out_size, void* d_ws, size_t ws_size,
                              hipStream_t stream)
{
  const float* x0    = (const float*)d_in[0];
  const float* x1    = (const float*)d_in[1];
  const float* x2    = (const float*)d_in[2];
  const float* smask = (const float*)d_in[3];
  const float* Wp0   = (const float*)d_in[4];
  const float* bp0   = (const float*)d_in[5];
  const float* Wp1   = (const float*)d_in[6];
  const float* bp1   = (const float*)d_in[7];
  const float* Wp2   = (const float*)d_in[8];
  const float* bp2   = (const float*)d_in[9];
  const float* freq  = (const float*)d_in[10];
  const float* phem  = (const float*)d_in[11];
  const float* Ux    = (const float*)d_in[12];
  const float* Uh    = (const float*)d_in[13];
  const float* lamp  = (const float*)d_in[14];
  const float* kr    = (const float*)d_in[15];
  const float* ki    = (const float*)d_in[16];
  const float* W1    = (const float*)d_in[17];
  const float* b1    = (const float*)d_in[18];
  const float* W2    = (const float*)d_in[19];
  const float* b2    = (const float*)d_in[20];

  char* ws = (char*)d_ws;
  auto alignup = [](size_t x){ return (x + 255) & ~(size_t)255; };
  size_t off = 0;
  ushort_t* S   = (ushort_t*)(ws + off); off = alignup(off + (size_t)1920*16384*sizeof(ushort_t));
  float* Qbuf   = (float*)(ws + off);    off = alignup(off + (size_t)6*BT*DD*sizeof(float));
  float* Wgt    = (float*)(ws + off);    off = alignup(off + (size_t)BT*3*sizeof(float));
  float* Vr     = (float*)(ws + off);    off = alignup(off + (size_t)DD*DD*sizeof(float));
  float* Vi     = (float*)(ws + off);    off = alignup(off + (size_t)DD*DD*sizeof(float));
  ushort_t* UxTh = (ushort_t*)(ws + off); off = alignup(off + (size_t)DD*DD*sizeof(ushort_t));
  ushort_t* UxTl = (ushort_t*)(ws + off); off = alignup(off + (size_t)DD*DD*sizeof(ushort_t));
  float* Probs  = (float*)(ws + off);    off = alignup(off + (size_t)BT*DD*sizeof(float));
  ushort_t* PpH = (ushort_t*)(ws + off); off = alignup(off + (size_t)6*16384*sizeof(ushort_t));
  ushort_t* PpL = (ushort_t*)(ws + off); off = alignup(off + (size_t)6*16384*sizeof(ushort_t));
  ushort_t* PTh = (ushort_t*)(ws + off); off = alignup(off + (size_t)6*16384*sizeof(ushort_t));
  ushort_t* PTl = (ushort_t*)(ws + off); off = alignup(off + (size_t)6*16384*sizeof(ushort_t));
  ushort_t* Mh  = (ushort_t*)(ws + off); off = alignup(off + (size_t)60*16384*sizeof(ushort_t));
  ushort_t* Wmh = (ushort_t*)(ws + off); off = alignup(off + (size_t)120*16384*sizeof(ushort_t));
  ushort_t* GTh = (ushort_t*)(ws + off); off = alignup(off + (size_t)60*16384*sizeof(ushort_t));
  ushort_t* GTl = (ushort_t*)(ws + off); off = alignup(off + (size_t)60*16384*sizeof(ushort_t));
  (void)ws_size; (void)in_sizes; (void)n_in; (void)out_size;

  k_small<<<384, 128, 0, stream>>>(Ux, Uh, kr, ki, UxTh, UxTl, Vr, Vi, PpH, PpL, PTh, PTl);
  k_prep<<<BT, 128, 0, stream>>>(x0, x1, x2, smask, Wp0, bp0, Wp1, bp1, Wp2, bp2, freq, phem, Ux, Qbuf, Wgt);
  k_pow2<<<1, 256, 0, stream>>>(PpH, PpL, PTh, PTl);
  k_gchain<<<60, 256, 0, stream>>>(PpH, PpL, PTh, PTl, GTh, GTl);
  k_precompMW<<<180, 256, 0, stream>>>(GTh, GTl, UxTh, UxTl, Vr, Vi, Mh, Wmh);
  k_conjL1<<<1920, 512, 0, stream>>>(S, GTh, Qbuf, Wgt);
  k_prefix<<<512, 256, 0, stream>>>(S, lamp);
  k_conjmid<<<1920, 512, 0, stream>>>(S, Mh, lamp);
  k_prefix<<<512, 256, 0, stream>>>(S, lamp);
  k_meas<<<3840, 512, 0, stream>>>(S, Wmh, lamp, Probs);
  k_head<<<BT, 64, 0, stream>>>(Probs, W1, b1, W2, b2, (float*)d_out);
}

// Round 11
// 413.211 us; speedup vs baseline: 1.5950x; 1.1326x over previous
//
#include <hip/hip_runtime.h>

// QMN B=32,T=60,D=128. Round 11.
// r10: symmetry fold (C = Sr+Si) landed; new top = k_pow2 (1 block, 100us,
// VGPR=256, 128 scalar 2B scattered global stores/thread/iter).
// Changes (power chain only, no math change):
//  - k_pow2 -> 5x k_pow2step (2 blk x 512 thr): plain layout via A=PT,B=Pp +
//    transposed-emit; transposed layout via A=Pp,B=PT + transposed-emit.
//    All-vector emits, 2x4 tiles (low VGPR).
//  - k_gchain: flipped iteration gemm(A=PT_k, B=A_run)+emit_t keeps running
//    product plain with vector stores; final factor in normal orientation
//    emits GT directly. 512 thr.

#define DB 32
#define DT 60
#define DD 128
#define BT (DB*DT)
#define SP 136
#define BSTR 36

typedef unsigned short ushort_t;
typedef __attribute__((ext_vector_type(8))) __bf16 bf16x8;
typedef __attribute__((ext_vector_type(4))) float  float4v;

__device__ __forceinline__ float bf2f(ushort_t u){
  union { unsigned int i; float f; } x; x.i = ((unsigned int)u) << 16; return x.f;
}
__device__ __forceinline__ ushort_t f2bf(float f){
  union { float f; unsigned int i; } x; x.f = f;
  unsigned int lsb = (x.i >> 16) & 1u;
  return (ushort_t)((x.i + 0x7FFFu + lsb) >> 16);
}
__device__ __forceinline__ unsigned int f2bfpk(float a, float b){
#if defined(__gfx950__) && __has_builtin(__builtin_amdgcn_cvt_pk_bf16_f32)
  auto v = __builtin_amdgcn_cvt_pk_bf16_f32(a, b);
  unsigned int r; __builtin_memcpy(&r, &v, 4); return r;
#else
  return (unsigned int)f2bf(a) | ((unsigned int)f2bf(b) << 16);
#endif
}
__device__ __forceinline__ void split2(float v, ushort_t& h, ushort_t& l){
  h = f2bf(v); l = f2bf(v - bf2f(h));
}

// D[m][n] = sum_k A[m][k]*B[n][k]
template<int RT, int CT, bool ALO, bool BLO>
__device__ __forceinline__ void gemm_t(const ushort_t* Ah, const ushort_t* Al,
                                       const ushort_t* Bh, const ushort_t* Bl,
                                       float4v* acc, int row0, int col0, int gma, int q)
{
  for (int ks = 0; ks < 4; ks++){
    int ko = ks*32 + q*8;
    bf16x8 aF[RT], aL[RT], bF[CT], bL[CT];
    #pragma unroll
    for (int R = 0; R < RT; R++){
      int row = row0 + 16*R + gma;
      aF[R] = *(const bf16x8*)&Ah[row*SP + ko];
      if (ALO) aL[R] = *(const bf16x8*)&Al[row*SP + ko];
    }
    #pragma unroll
    for (int C = 0; C < CT; C++){
      int row = col0 + 16*C + gma;
      bF[C] = *(const bf16x8*)&Bh[row*SP + ko];
      if (BLO) bL[C] = *(const bf16x8*)&Bl[row*SP + ko];
    }
    #pragma unroll
    for (int R = 0; R < RT; R++)
      #pragma unroll
      for (int C = 0; C < CT; C++){
        float4v c = acc[R*CT+C];
        c = __builtin_amdgcn_mfma_f32_16x16x32_bf16(aF[R], bF[C], c, 0, 0, 0);
        if (BLO) c = __builtin_amdgcn_mfma_f32_16x16x32_bf16(aF[R], bL[C], c, 0, 0, 0);
        if (ALO) c = __builtin_amdgcn_mfma_f32_16x16x32_bf16(aL[R], bF[C], c, 0, 0, 0);
        acc[R*CT+C] = c;
      }
  }
}

// transposed store computed(m,n) -> dst[n*stride + m]
template<int RT, int CT>
__device__ __forceinline__ void emit_t(const float4v* acc, ushort_t* dst, int stride,
                                       int row0, int col0, int gma, int q){
  #pragma unroll
  for (int R = 0; R < RT; R++)
    #pragma unroll
    for (int C = 0; C < CT; C++){
      int c = col0 + 16*C + gma, r0 = row0 + 16*R + 4*q;
      uint2 o;
      o.x = f2bfpk(acc[R*CT+C][0], acc[R*CT+C][1]);
      o.y = f2bfpk(acc[R*CT+C][2], acc[R*CT+C][3]);
      *(uint2*)&dst[(size_t)c*stride + r0] = o;
    }
}
// transposed hi/lo split store
template<int RT, int CT>
__device__ __forceinline__ void emit_split_t(const float4v* acc, ushort_t* dh, ushort_t* dl, int stride,
                                             int row0, int col0, int gma, int q){
  #pragma unroll
  for (int R = 0; R < RT; R++)
    #pragma unroll
    for (int C = 0; C < CT; C++){
      int c = col0 + 16*C + gma, r0 = row0 + 16*R + 4*q;
      ushort4 hh, ll;
      split2(acc[R*CT+C][0], hh.x, ll.x); split2(acc[R*CT+C][1], hh.y, ll.y);
      split2(acc[R*CT+C][2], hh.z, ll.z); split2(acc[R*CT+C][3], hh.w, ll.w);
      *(ushort4*)&dh[(size_t)c*stride + r0] = hh;
      *(ushort4*)&dl[(size_t)c*stride + r0] = ll;
    }
}
template<int NT>
__device__ __forceinline__ void lds_load_mat(ushort_t* dst, const ushort_t* src, int tid){
  for (int i = tid*4; i < 16384; i += NT*4){
    int r = i >> 7, k = i & 127;
    *(ushort4*)&dst[r*SP + k] = *(const ushort4*)&src[i];
  }
}
template<int NT>
__device__ __forceinline__ void lds_store_mat(ushort_t* dst, const ushort_t* src, int tid){
  for (int i = tid*4; i < 16384; i += NT*4){
    int r = i >> 7, k = i & 127;
    *(ushort4*)&dst[i] = *(const ushort4*)&src[r*SP + k];
  }
}

// ---- small: prepU | normv | initG ----
__global__ void k_small(const float* Ux, const float* Uh, const float* kr, const float* ki,
                        ushort_t* UxTh, ushort_t* UxTl, float* Vr, float* Vi,
                        ushort_t* PpH, ushort_t* PpL, ushort_t* PTh, ushort_t* PTl){
  int blk = blockIdx.x, d = threadIdx.x;
  if (blk < 128){
    int i = blk;
    float v = Ux[i*DD + d];
    ushort_t h, l; split2(v, h, l);
    UxTh[d*DD + i] = h; UxTl[d*DD + i] = l;
  } else if (blk < 256){
    __shared__ float red[DD];
    int k = blk - 128;
    float r = kr[k*DD+d], im = ki[k*DD+d];
    red[d] = r*r + im*im;
    __syncthreads();
    for (int s = 64; s > 0; s >>= 1){ if (d < s) red[d] += red[d+s]; __syncthreads(); }
    float nrm = fmaxf(sqrtf(red[0]), 1e-12f);
    Vr[k*DD+d] = r/nrm; Vi[k*DD+d] = im/nrm;
  } else {
    int i = blk - 256;
    float v = Uh[i*DD + d];
    ushort_t h, l; split2(v, h, l);
    PpH[i*DD + d] = h;  PpL[i*DD + d] = l;
    PTh[d*DD + i] = h;  PTl[d*DD + i] = l;
  }
}

// ---- pow2step: from G^h (slot s-1) compute G^{2h} (slot s); all-vector ----
__global__ __launch_bounds__(512,1) void k_pow2step(ushort_t* PpH, ushort_t* PpL,
                                                    ushort_t* PTh, ushort_t* PTl, int s){
  __shared__ ushort_t Ah[128*SP], Al[128*SP], Bh[128*SP], Bl[128*SP];
  int which = blockIdx.x;   // 0: produce plain Pp[s]; 1: produce transposed PT[s]
  size_t src = (size_t)(s-1)*16384, dst = (size_t)s*16384;
  int tid = threadIdx.x;
  int w = tid >> 6, lane = tid & 63, gma = lane & 15, q = lane >> 4;
  int row0 = 32*(w >> 1), col0 = 64*(w & 1);
  if (which == 0){            // A=PT, B=Pp: D[m][n]=G2[n][m]; emit_t => plain
    lds_load_mat<512>(Ah, PTh + src, tid); lds_load_mat<512>(Al, PTl + src, tid);
    lds_load_mat<512>(Bh, PpH + src, tid); lds_load_mat<512>(Bl, PpL + src, tid);
  } else {                    // A=Pp, B=PT: D[m][n]=G2[m][n]; emit_t => transposed
    lds_load_mat<512>(Ah, PpH + src, tid); lds_load_mat<512>(Al, PpL + src, tid);
    lds_load_mat<512>(Bh, PTh + src, tid); lds_load_mat<512>(Bl, PTl + src, tid);
  }
  __syncthreads();
  float4v acc[8];
  #pragma unroll
  for (int i = 0; i < 8; i++) acc[i] = (float4v){0.f,0.f,0.f,0.f};
  gemm_t<2,4,true,true>(Ah, Al, Bh, Bl, acc, row0, col0, gma, q);
  if (which == 0) emit_split_t<2,4>(acc, PpH + dst, PpL + dst, 128, row0, col0, gma, q);
  else            emit_split_t<2,4>(acc, PTh + dst, PTl + dst, 128, row0, col0, gma, q);
}

// ---- gchain: block t composes G_t from binary powers (all-vector emits) ----
__global__ __launch_bounds__(512,1) void k_gchain(const ushort_t* PpH, const ushort_t* PpL,
                                                  const ushort_t* PTh, const ushort_t* PTl,
                                                  ushort_t* GTh, ushort_t* GTl){
  __shared__ ushort_t Ah[128*SP], Al[128*SP], Bh[128*SP], Bl[128*SP];
  int t = blockIdx.x;
  int tid = threadIdx.x;
  int w = tid >> 6, lane = tid & 63, gma = lane & 15, q = lane >> 4;
  int row0 = 32*(w >> 1), col0 = 64*(w & 1);
  size_t gslot = (size_t)t * 16384;
  if (t == 0){
    for (int i = tid*4; i < 16384; i += 2048){
      int r = i >> 7, k = i & 127;
      ushort4 zz; zz.x = zz.y = zz.z = zz.w = 0;
      *(ushort4*)&GTl[gslot + i] = zz;
      ushort4 oh;
      oh.x = (r == (k+0)) ? (ushort_t)0x3F80 : (ushort_t)0;
      oh.y = (r == (k+1)) ? (ushort_t)0x3F80 : (ushort_t)0;
      oh.z = (r == (k+2)) ? (ushort_t)0x3F80 : (ushort_t)0;
      oh.w = (r == (k+3)) ? (ushort_t)0x3F80 : (ushort_t)0;
      *(ushort4*)&GTh[gslot + i] = oh;
    }
    return;
  }
  int b0 = __ffs(t) - 1;
  int rem = t & ~(1 << b0);
  if (rem == 0){
    size_t ps = (size_t)b0 * 16384;
    for (int i = tid*4; i < 16384; i += 2048){
      *(ushort4*)&GTh[gslot + i] = *(const ushort4*)&PTh[ps + i];
      *(ushort4*)&GTl[gslot + i] = *(const ushort4*)&PTl[ps + i];
    }
    return;
  }
  // running product A_run = G^{2^b0} plain (hi/lo) in Ah/Al
  lds_load_mat<512>(Ah, PpH + (size_t)b0*16384, tid);
  lds_load_mat<512>(Al, PpL + (size_t)b0*16384, tid);
  while (rem){
    int k = __ffs(rem) - 1;
    rem &= ~(1 << k);
    lds_load_mat<512>(Bh, PTh + (size_t)k*16384, tid);
    lds_load_mat<512>(Bl, PTl + (size_t)k*16384, tid);
    __syncthreads();
    float4v acc[8];
    #pragma unroll
    for (int i = 0; i < 8; i++) acc[i] = (float4v){0.f,0.f,0.f,0.f};
    if (rem){
      // flipped: D[m][n] = sum PT_k[m][.]*Arun[n][.] = (Arun*P)[n][m]
      gemm_t<2,4,true,true>(Bh, Bl, Ah, Al, acc, row0, col0, gma, q);
      __syncthreads();
      emit_split_t<2,4>(acc, Ah, Al, SP, row0, col0, gma, q);   // Arun <- Arun*P (plain)
      __syncthreads();
    } else {
      // final: normal orientation, emit_t => transposed = GT_t
      gemm_t<2,4,true,true>(Ah, Al, Bh, Bl, acc, row0, col0, gma, q);
      emit_split_t<2,4>(acc, GTh + gslot, GTl + gslot, 128, row0, col0, gma, q);
    }
  }
}

// ---- precompMW ----
__global__ __launch_bounds__(256,1) void k_precompMW(const ushort_t* GTh, const ushort_t* GTl,
                                                     const ushort_t* UxTh, const ushort_t* UxTl,
                                                     const float* Vr, const float* Vi,
                                                     ushort_t* Mh, ushort_t* Wh){
  __shared__ ushort_t Bh[128*SP], Bl[128*SP], Ah[128*SP], Al[128*SP];
  int blk = blockIdx.x;
  int tid = threadIdx.x;
  int w = tid >> 6, lane = tid & 63, gma = lane & 15, q = lane >> 4;
  int row0 = 64*(w >> 1), col0 = 64*(w & 1);
  if (blk < 60){
    int t = blk;
    lds_load_mat<256>(Bh, GTh + (size_t)t*16384, tid);
    lds_load_mat<256>(Bl, GTl + (size_t)t*16384, tid);
    lds_load_mat<256>(Ah, UxTh, tid);
    lds_load_mat<256>(Al, UxTl, tid);
    __syncthreads();
    float4v acc[16];
    #pragma unroll
    for (int i = 0; i < 16; i++) acc[i] = (float4v){0.f,0.f,0.f,0.f};
    gemm_t<4,4,true,true>(Ah, Al, Bh, Bl, acc, row0, col0, gma, q);
    __syncthreads();
    emit_split_t<4,4>(acc, Ah, Al, SP, row0, col0, gma, q);
    __syncthreads();
    #pragma unroll
    for (int i = 0; i < 16; i++) acc[i] = (float4v){0.f,0.f,0.f,0.f};
    gemm_t<4,4,true,true>(Bh, Bl, Ah, Al, acc, row0, col0, gma, q);
    #pragma unroll
    for (int R = 0; R < 4; R++)
      #pragma unroll
      for (int C = 0; C < 4; C++){
        int c = col0 + 16*C + gma, r0 = row0 + 16*R + 4*q;
        uint2 o;
        o.x = f2bfpk(acc[R*4+C][0], acc[R*4+C][1]);
        o.y = f2bfpk(acc[R*4+C][2], acc[R*4+C][3]);
        *(uint2*)&Mh[(size_t)t*16384 + c*128 + r0] = o;
      }
  } else {
    int bx = blk - 60;
    int t = bx >> 1, which = bx & 1;
    lds_load_mat<256>(Ah, GTh + (size_t)t*16384, tid);
    lds_load_mat<256>(Al, GTl + (size_t)t*16384, tid);
    const float* V = which ? Vi : Vr;
    for (int i = tid; i < 16384; i += 256){
      int r = i >> 7, k = i & 127;
      ushort_t h, l; split2(V[i], h, l);
      Bh[r*SP + k] = h; Bl[r*SP + k] = l;
    }
    __syncthreads();
    float4v acc[16];
    #pragma unroll
    for (int i = 0; i < 16; i++) acc[i] = (float4v){0.f,0.f,0.f,0.f};
    gemm_t<4,4,true,true>(Ah, Al, Bh, Bl, acc, row0, col0, gma, q);
    #pragma unroll
    for (int R = 0; R < 4; R++)
      #pragma unroll
      for (int C = 0; C < 4; C++){
        int c = col0 + 16*C + gma, r0 = row0 + 16*R + 4*q;
        uint2 o;
        o.x = f2bfpk(acc[R*4+C][0], acc[R*4+C][1]);
        o.y = f2bfpk(acc[R*4+C][2], acc[R*4+C][3]);
        *(uint2*)&Wh[(size_t)bx*16384 + c*128 + r0] = o;
      }
  }
}

// ---- prep (fused qtrans) ----
__global__ __launch_bounds__(128) void k_prep(
    const float* x0, const float* x1, const float* x2, const float* smask,
    const float* Wp0, const float* bp0, const float* Wp1, const float* bp1,
    const float* Wp2, const float* bp2, const float* freq, const float* phem,
    const float* Ux, float* Q, float* Wgt)
{
  __shared__ float xs[768+74+35];
  __shared__ float red[DD];
  __shared__ float nrm3[3];
  __shared__ float ps[6][DD];
  int bt = blockIdx.x; int t = bt % DT;
  int d = threadIdx.x;
  const float* r0 = x0 + (size_t)bt*768;
  for (int k = d; k < 768; k += DD) xs[k] = r0[k];
  const float* r1 = x1 + (size_t)bt*74;
  if (d < 74) xs[768+d] = r1[d];
  const float* r2 = x2 + (size_t)bt*35;
  if (d < 35) xs[768+74+d] = r2[d];
  __syncthreads();
  float rep[3];
  { float acc = bp0[d]; for (int k = 0; k < 768; k++) acc += xs[k]*Wp0[k*DD+d]; rep[0] = fmaxf(acc, 0.f); }
  { float acc = bp1[d]; for (int k = 0; k < 74; k++) acc += xs[768+k]*Wp1[k*DD+d]; rep[1] = fmaxf(acc, 0.f); }
  { float acc = bp2[d]; for (int k = 0; k < 35; k++) acc += xs[768+74+k]*Wp2[k*DD+d]; rep[2] = fmaxf(acc, 0.f); }
  for (int m = 0; m < 3; m++){
    red[d] = rep[m]*rep[m];
    __syncthreads();
    for (int s = 64; s > 0; s >>= 1){ if (d < s) red[d] += red[d+s]; __syncthreads(); }
    if (d == 0) nrm3[m] = sqrtf(red[0]);
    __syncthreads();
  }
  float n0 = nrm3[0], n1 = nrm3[1], n2 = nrm3[2];
  float mx = fmaxf(n0, fmaxf(n1, n2));
  float e0 = expf(n0-mx), e1 = expf(n1-mx), e2 = expf(n2-mx);
  float einv = 1.f/(e0+e1+e2);
  if (d < 3) Wgt[bt*3+d] = (d==0?e0:(d==1?e1:e2))*einv;
  float s0 = smask[bt*2], s1 = smask[bt*2+1];
  int id = (s1 > s0) ? 1 : 0;
  float ph = (float)t * freq[id*DD+d] + phem[id*DD+d];
  float cp = cosf(ph), sp = sinf(ph);
  for (int m = 0; m < 3; m++){
    float a = rep[m] / fmaxf(nrm3[m], 1e-12f);
    ps[m][d]   = a*cp;
    ps[3+m][d] = a*sp;
  }
  __syncthreads();
  float qv[6] = {0.f,0.f,0.f,0.f,0.f,0.f};
  const float* uxr = Ux + (size_t)d*DD;
  for (int p = 0; p < DD; p++){
    float u = uxr[p];
    #pragma unroll
    for (int j = 0; j < 6; j++) qv[j] += u * ps[j][p];
  }
  #pragma unroll
  for (int j = 0; j < 6; j++)
    Q[((size_t)(j*BT) + bt)*DD + d] = qv[j];
}

// ---- conjL1 (512 thr, per (t,b)): C = Xr+Xi via rank-6 MFMA, S <- G^T C G ----
__global__ __launch_bounds__(512,4) void k_conjL1(ushort_t* S, const ushort_t* GTh,
                                                  const float* Q, const float* Wgt){
  __shared__ ushort_t Bh[128*SP], Xs[128*SP];
  __shared__ float wl[3];
  ushort_t* Bstage = Xs;
  int blk = blockIdx.x;            // t*DB+b
  int t = blk >> 5, b = blk & 31;
  int bt_in = b*DT + t;
  size_t slot = (size_t)blk * 16384;
  int tid = threadIdx.x;
  int w = tid >> 6, lane = tid & 63, gma = lane & 15, q = lane >> 4;
  int row0 = 32*(w >> 1), col0 = 64*(w & 1);
  lds_load_mat<512>(Bh, GTh + (size_t)t*16384, tid);
  for (int i = tid*4; i < 128*BSTR; i += 2048){
    ushort4 z; z.x = z.y = z.z = z.w = 0;
    *(ushort4*)&Bstage[i] = z;
  }
  if (tid < 3) wl[tid] = Wgt[bt_in*3 + tid];
  __syncthreads();
  for (int l = tid; l < 6*DD; l += 512){
    int j = l >> 7, r = l & 127;
    Bstage[r*BSTR + j] = f2bf(Q[((size_t)(j*BT) + bt_in)*DD + r]);
  }
  __syncthreads();
  float4v acc[8];
  {
    float w0 = wl[0], w1 = wl[1], w2 = wl[2];
    bf16x8 aF[2], bF[4];
    #pragma unroll
    for (int R = 0; R < 2; R++){
      int r = row0 + 16*R + gma;
      aF[R] = *(const bf16x8*)&Bstage[r*BSTR + q*8];
    }
    #pragma unroll
    for (int C = 0; C < 4; C++){
      int c = col0 + 16*C + gma;
      bf16x8 braw = *(const bf16x8*)&Bstage[c*BSTR + q*8];
      const ushort_t* bu = (const ushort_t*)&braw;
      union { ushort_t u[8]; bf16x8 v; } au;
      #pragma unroll
      for (int j = 0; j < 8; j++) au.u[j] = 0;
      if (q == 0){
        float b0 = bf2f(bu[0]), b1 = bf2f(bu[1]), b2 = bf2f(bu[2]);
        float b3 = bf2f(bu[3]), b4 = bf2f(bu[4]), b5 = bf2f(bu[5]);
        au.u[0] = f2bf(w0*(b0+b3)); au.u[1] = f2bf(w1*(b1+b4)); au.u[2] = f2bf(w2*(b2+b5));
        au.u[3] = f2bf(w0*(b3-b0)); au.u[4] = f2bf(w1*(b4-b1)); au.u[5] = f2bf(w2*(b5-b2));
      }
      bF[C] = au.v;
    }
    #pragma unroll
    for (int i = 0; i < 8; i++) acc[i] = (float4v){0.f,0.f,0.f,0.f};
    #pragma unroll
    for (int R = 0; R < 2; R++)
      #pragma unroll
      for (int C = 0; C < 4; C++)
        acc[R*4+C] = __builtin_amdgcn_mfma_f32_16x16x32_bf16(aF[R], bF[C], acc[R*4+C], 0, 0, 0);
  }
  __syncthreads();
  emit_t<2,4>(acc, Xs, SP, row0, col0, gma, q);              // Xs = C (true)
  __syncthreads();
  #pragma unroll
  for (int i = 0; i < 8; i++) acc[i] = (float4v){0.f,0.f,0.f,0.f};
  gemm_t<2,4,false,false>(Xs, Xs, Bh, Bh, acc, row0, col0, gma, q);
  __syncthreads();
  emit_t<2,4>(acc, Xs, SP, row0, col0, gma, q);              // Xs = G^T C^T
  __syncthreads();
  #pragma unroll
  for (int i = 0; i < 8; i++) acc[i] = (float4v){0.f,0.f,0.f,0.f};
  gemm_t<2,4,false,false>(Xs, Xs, Bh, Bh, acc, row0, col0, gma, q);
  __syncthreads();
  emit_t<2,4>(acc, Xs, SP, row0, col0, gma, q);              // Xs = G^T C G
  __syncthreads();
  lds_store_mat<512>(S + slot, Xs, tid);
}

// ---- prefix: Z_t = lam*Z_{t-1} + Y_t (32 chains) ----
__global__ __launch_bounds__(256) void k_prefix(ushort_t* S, const float* lamp){
  int blk = blockIdx.x;            // 512 = 32 chains x 16 slabs
  int chain = blk >> 4, slab = blk & 15;
  int tid = threadIdx.x;
  size_t off = (size_t)slab*1024 + tid*4;
  float lam = lamp[0];
  float a0=0.f, a1=0.f, a2=0.f, a3=0.f;
  size_t addr = (size_t)chain*16384 + off;
  const size_t step = (size_t)32*16384;
  ushort4 nxt = *(const ushort4*)&S[addr];
  for (int t = 0; t < DT; t++){
    ushort4 u = nxt;
    if (t < DT-1) nxt = *(const ushort4*)&S[addr + step];
    a0 = lam*a0 + bf2f(u.x); a1 = lam*a1 + bf2f(u.y);
    a2 = lam*a2 + bf2f(u.z); a3 = lam*a3 + bf2f(u.w);
    uint2 o; o.x = f2bfpk(a0, a1); o.y = f2bfpk(a2, a3);
    *(uint2*)&S[addr] = o;
    addr += step;
  }
}

// ---- conjmid (512 thr, per (t,b)): S <- (1-l) M S M^T + c_t I ----
__global__ __launch_bounds__(512,4) void k_conjmid(ushort_t* S, const ushort_t* Mh,
                                                   const float* lamp){
  __shared__ ushort_t Bh[128*SP], Zs[128*SP];
  int blk = blockIdx.x;
  int t = blk >> 5;
  size_t slot = (size_t)blk * 16384;
  int tid = threadIdx.x;
  int w = tid >> 6, lane = tid & 63, gma = lane & 15, q = lane >> 4;
  int row0 = 32*(w >> 1), col0 = 64*(w & 1);
  lds_load_mat<512>(Bh, Mh + (size_t)t*16384, tid);
  lds_load_mat<512>(Zs, S + slot, tid);
  __syncthreads();
  float lam = lamp[0];
  float oml = 1.f - lam;
  float ct = powf(lam, (float)(t+1)) / 128.f;
  float4v acc[8];
  #pragma unroll
  for (int i = 0; i < 8; i++) acc[i] = (float4v){0.f,0.f,0.f,0.f};
  gemm_t<2,4,false,false>(Zs, Zs, Bh, Bh, acc, row0, col0, gma, q);
  __syncthreads();
  emit_t<2,4>(acc, Zs, SP, row0, col0, gma, q);
  __syncthreads();
  #pragma unroll
  for (int i = 0; i < 8; i++) acc[i] = (float4v){0.f,0.f,0.f,0.f};
  gemm_t<2,4,false,false>(Zs, Zs, Bh, Bh, acc, row0, col0, gma, q);
  __syncthreads();
  #pragma unroll
  for (int R = 0; R < 2; R++)
    #pragma unroll
    for (int C = 0; C < 4; C++){
      int c = col0 + 16*C + gma, r0 = row0 + 16*R + 4*q;
      float v0 = oml*acc[R*4+C][0] + ((c == r0+0) ? ct : 0.f);
      float v1 = oml*acc[R*4+C][1] + ((c == r0+1) ? ct : 0.f);
      float v2 = oml*acc[R*4+C][2] + ((c == r0+2) ? ct : 0.f);
      float v3 = oml*acc[R*4+C][3] + ((c == r0+3) ? ct : 0.f);
      uint2 o; o.x = f2bfpk(v0, v1); o.y = f2bfpk(v2, v3);
      *(uint2*)&Zs[(size_t)c*SP + r0] = o;
    }
  __syncthreads();
  lds_store_mat<512>(S + slot, Zs, tid);
}

// ---- meas (512 thr, per (tb,h)): stage1 Vs*C^T then 16 diag tiles ----
__global__ __launch_bounds__(512,2) void k_meas(const ushort_t* S, const ushort_t* Wh,
                                                const float* lamp, float* Probs){
  __shared__ ushort_t Vs[128*SP], Ss[128*SP];
  __shared__ float Pd[64];
  int blk = blockIdx.x;
  int tb = blk >> 1, h = blk & 1;
  int t = tb >> 5;
  int tid = threadIdx.x;
  int w = tid >> 6, lane = tid & 63, gma = lane & 15, q = lane >> 4;
  int row0 = 32*(w >> 1), col0 = 64*(w & 1);
  size_t slot = (size_t)tb * 16384;
  size_t wbase = (size_t)(t*2) * 16384;
  for (int i = tid*4; i < 16384; i += 2048){
    int r = i >> 7, k = i & 127;
    size_t gsrc = wbase + ((r < 64) ? 0 : 16384) + (size_t)(64*h + (r & 63))*128 + k;
    *(ushort4*)&Vs[r*SP+k] = *(const ushort4*)&Wh[gsrc];
    *(ushort4*)&Ss[r*SP+k] = *(const ushort4*)&S[slot + i];
  }
  if (tid < 64) Pd[tid] = 0.f;
  __syncthreads();
  {
    float4v acc[8];
    #pragma unroll
    for (int i = 0; i < 8; i++) acc[i] = (float4v){0.f,0.f,0.f,0.f};
    gemm_t<2,4,false,false>(Ss, Ss, Vs, Vs, acc, row0, col0, gma, q);
    __syncthreads();
    emit_t<2,4>(acc, Ss, SP, row0, col0, gma, q);            // Ss = Vs * C^T
  }
  __syncthreads();
  #pragma unroll
  for (int g = 0; g < 2; g++){
    int ti = 2*w + g;                  // 16 tiles over 8 waves
    int grp = ti >> 2, sub = ti & 3;
    int arow = (((grp == 1) || (grp == 2)) ? 64 : 0) + 16*sub + gma;
    int brow = (((grp == 1) || (grp == 3)) ? 64 : 0) + 16*sub + gma;
    float coef = (grp == 2) ? -1.f : 1.f;
    float4v a1 = (float4v){0.f,0.f,0.f,0.f};
    #pragma unroll
    for (int ks = 0; ks < 4; ks++){
      int ko = ks*32 + q*8;
      bf16x8 aF = *(const bf16x8*)&Ss[arow*SP + ko];
      bf16x8 bF = *(const bf16x8*)&Vs[brow*SP + ko];
      a1 = __builtin_amdgcn_mfma_f32_16x16x32_bf16(aF, bF, a1, 0, 0, 0);
    }
    if ((gma >> 2) == q) atomicAdd(&Pd[16*sub + gma], coef * a1[gma & 3]);
  }
  __syncthreads();
  if (tid < 64){
    float lam = lamp[0];
    float ct = powf(lam, (float)(t+1)) / 128.f;
    Probs[(size_t)tb*DD + 64*h + tid] = (1.f - lam)*Pd[tid] + ct;
  }
}

// ---- head ----
__global__ __launch_bounds__(64) void k_head(const float* Probs, const float* W1, const float* b1,
                        const float* W2, const float* b2, float* out)
{
  __shared__ float ps[DD];
  __shared__ float hid[64];
  __shared__ float ov[4];
  int tb = blockIdx.x;
  int tid = threadIdx.x;
  ps[tid] = Probs[(size_t)tb*DD + tid];
  ps[tid+64] = Probs[(size_t)tb*DD + 64 + tid];
  __syncthreads();
  float acc = b1[tid];
  for (int dd = 0; dd < DD; dd++) acc += ps[dd]*W1[dd*64 + tid];
  hid[tid] = fmaxf(acc, 0.f);
  __syncthreads();
  if (tid < 4){
    float o = b2[tid];
    for (int j = 0; j < 64; j++) o += hid[j]*W2[j*4 + tid];
    ov[tid] = tanhf(o);
  }
  __syncthreads();
  if (tid == 0){
    float m = fmaxf(fmaxf(ov[0],ov[1]), fmaxf(ov[2],ov[3]));
    float lse = logf(expf(ov[0]-m)+expf(ov[1]-m)+expf(ov[2]-m)+expf(ov[3]-m));
    int t = tb >> 5, b = tb & 31;
    float* o = out + ((size_t)(b*DT + t))*4;
    o[0] = ov[0]-m-lse; o[1] = ov[1]-m-lse;
    o[2] = ov[2]-m-lse; o[3] = ov[3]-m-lse;
  }
}

extern "C" void kernel_launch(void* const* d_in, const int* in_sizes, int n_in,
                              void* d_out, int out_size, void* d_ws, size_t ws_size,
                              hipStream_t stream)
{
  const float* x0    = (const float*)d_in[0];
  const float* x1    = (const float*)d_in[1];
  const float* x2    = (const float*)d_in[2];
  const float* smask = (const float*)d_in[3];
  const float* Wp0   = (const float*)d_in[4];
  const float* bp0   = (const float*)d_in[5];
  const float* Wp1   = (const float*)d_in[6];
  const float* bp1   = (const float*)d_in[7];
  const float* Wp2   = (const float*)d_in[8];
  const float* bp2   = (const float*)d_in[9];
  const float* freq  = (const float*)d_in[10];
  const float* phem  = (const float*)d_in[11];
  const float* Ux    = (const float*)d_in[12];
  const float* Uh    = (const float*)d_in[13];
  const float* lamp  = (const float*)d_in[14];
  const float* kr    = (const float*)d_in[15];
  const float* ki    = (const float*)d_in[16];
  const float* W1    = (const float*)d_in[17];
  const float* b1    = (const float*)d_in[18];
  const float* W2    = (const float*)d_in[19];
  const float* b2    = (const float*)d_in[20];

  char* ws = (char*)d_ws;
  auto alignup = [](size_t x){ return (x + 255) & ~(size_t)255; };
  size_t off = 0;
  ushort_t* S   = (ushort_t*)(ws + off); off = alignup(off + (size_t)1920*16384*sizeof(ushort_t));
  float* Qbuf   = (float*)(ws + off);    off = alignup(off + (size_t)6*BT*DD*sizeof(float));
  float* Wgt    = (float*)(ws + off);    off = alignup(off + (size_t)BT*3*sizeof(float));
  float* Vr     = (float*)(ws + off);    off = alignup(off + (size_t)DD*DD*sizeof(float));
  float* Vi     = (float*)(ws + off);    off = alignup(off + (size_t)DD*DD*sizeof(float));
  ushort_t* UxTh = (ushort_t*)(ws + off); off = alignup(off + (size_t)DD*DD*sizeof(ushort_t));
  ushort_t* UxTl = (ushort_t*)(ws + off); off = alignup(off + (size_t)DD*DD*sizeof(ushort_t));
  float* Probs  = (float*)(ws + off);    off = alignup(off + (size_t)BT*DD*sizeof(float));
  ushort_t* PpH = (ushort_t*)(ws + off); off = alignup(off + (size_t)6*16384*sizeof(ushort_t));
  ushort_t* PpL = (ushort_t*)(ws + off); off = alignup(off + (size_t)6*16384*sizeof(ushort_t));
  ushort_t* PTh = (ushort_t*)(ws + off); off = alignup(off + (size_t)6*16384*sizeof(ushort_t));
  ushort_t* PTl = (ushort_t*)(ws + off); off = alignup(off + (size_t)6*16384*sizeof(ushort_t));
  ushort_t* Mh  = (ushort_t*)(ws + off); off = alignup(off + (size_t)60*16384*sizeof(ushort_t));
  ushort_t* Wmh = (ushort_t*)(ws + off); off = alignup(off + (size_t)120*16384*sizeof(ushort_t));
  ushort_t* GTh = (ushort_t*)(ws + off); off = alignup(off + (size_t)60*16384*sizeof(ushort_t));
  ushort_t* GTl = (ushort_t*)(ws + off); off = alignup(off + (size_t)60*16384*sizeof(ushort_t));
  (void)ws_size; (void)in_sizes; (void)n_in; (void)out_size;

  k_small<<<384, 128, 0, stream>>>(Ux, Uh, kr, ki, UxTh, UxTl, Vr, Vi, PpH, PpL, PTh, PTl);
  k_prep<<<BT, 128, 0, stream>>>(x0, x1, x2, smask, Wp0, bp0, Wp1, bp1, Wp2, bp2, freq, phem, Ux, Qbuf, Wgt);
  for (int s = 1; s <= 5; s++)
    k_pow2step<<<2, 512, 0, stream>>>(PpH, PpL, PTh, PTl, s);
  k_gchain<<<60, 512, 0, stream>>>(PpH, PpL, PTh, PTl, GTh, GTl);
  k_precompMW<<<180, 256, 0, stream>>>(GTh, GTl, UxTh, UxTl, Vr, Vi, Mh, Wmh);
  k_conjL1<<<1920, 512, 0, stream>>>(S, GTh, Qbuf, Wgt);
  k_prefix<<<512, 256, 0, stream>>>(S, lamp);
  k_conjmid<<<1920, 512, 0, stream>>>(S, Mh, lamp);
  k_prefix<<<512, 256, 0, stream>>>(S, lamp);
  k_meas<<<3840, 512, 0, stream>>>(S, Wmh, lamp, Probs);
  k_head<<<BT, 64, 0, stream>>>(Probs, W1, b1, W2, b2, (float*)d_out);
}

// Round 12
// 410.428 us; speedup vs baseline: 1.6058x; 1.0068x over previous
//
#include <hip/hip_runtime.h>

// QMN B=32,T=60,D=128. Round 12: rank-6 factored layer-1 conjugation.
// C_t,b = sum_j combo_j raw_j^T (rank 6); G^T C G = sum_j (G^T combo)(G^T raw)^T
// and combos are linear in q => only A'_j = G^T q_j (6 vecs) need transforming.
//  - k_conjL1 (1920 blk, 2x128^3 GEMM) -> k_vtrans (60 blk, one GEMM/t for all
//    192 (b,j) vectors; transposed-emit gives [vec][comp] layout, vector stores)
//  - Y never materialized: k_zbuild fuses rank-6 outer build + lambda-prefix,
//    writes Z directly (kills 126MB Y write+read and the first prefix kernel).
// Everything else = r11.

#define DB 32
#define DT 60
#define DD 128
#define BT (DB*DT)
#define SP 136

typedef unsigned short ushort_t;
typedef __attribute__((ext_vector_type(8))) __bf16 bf16x8;
typedef __attribute__((ext_vector_type(4))) float  float4v;

__device__ __forceinline__ float bf2f(ushort_t u){
  union { unsigned int i; float f; } x; x.i = ((unsigned int)u) << 16; return x.f;
}
__device__ __forceinline__ ushort_t f2bf(float f){
  union { float f; unsigned int i; } x; x.f = f;
  unsigned int lsb = (x.i >> 16) & 1u;
  return (ushort_t)((x.i + 0x7FFFu + lsb) >> 16);
}
__device__ __forceinline__ unsigned int f2bfpk(float a, float b){
#if defined(__gfx950__) && __has_builtin(__builtin_amdgcn_cvt_pk_bf16_f32)
  auto v = __builtin_amdgcn_cvt_pk_bf16_f32(a, b);
  unsigned int r; __builtin_memcpy(&r, &v, 4); return r;
#else
  return (unsigned int)f2bf(a) | ((unsigned int)f2bf(b) << 16);
#endif
}
__device__ __forceinline__ void split2(float v, ushort_t& h, ushort_t& l){
  h = f2bf(v); l = f2bf(v - bf2f(h));
}

// D[m][n] = sum_k A[m][k]*B[n][k]
template<int RT, int CT, bool ALO, bool BLO>
__device__ __forceinline__ void gemm_t(const ushort_t* Ah, const ushort_t* Al,
                                       const ushort_t* Bh, const ushort_t* Bl,
                                       float4v* acc, int row0, int col0, int gma, int q)
{
  for (int ks = 0; ks < 4; ks++){
    int ko = ks*32 + q*8;
    bf16x8 aF[RT], aL[RT], bF[CT], bL[CT];
    #pragma unroll
    for (int R = 0; R < RT; R++){
      int row = row0 + 16*R + gma;
      aF[R] = *(const bf16x8*)&Ah[row*SP + ko];
      if (ALO) aL[R] = *(const bf16x8*)&Al[row*SP + ko];
    }
    #pragma unroll
    for (int C = 0; C < CT; C++){
      int row = col0 + 16*C + gma;
      bF[C] = *(const bf16x8*)&Bh[row*SP + ko];
      if (BLO) bL[C] = *(const bf16x8*)&Bl[row*SP + ko];
    }
    #pragma unroll
    for (int R = 0; R < RT; R++)
      #pragma unroll
      for (int C = 0; C < CT; C++){
        float4v c = acc[R*CT+C];
        c = __builtin_amdgcn_mfma_f32_16x16x32_bf16(aF[R], bF[C], c, 0, 0, 0);
        if (BLO) c = __builtin_amdgcn_mfma_f32_16x16x32_bf16(aF[R], bL[C], c, 0, 0, 0);
        if (ALO) c = __builtin_amdgcn_mfma_f32_16x16x32_bf16(aL[R], bF[C], c, 0, 0, 0);
        acc[R*CT+C] = c;
      }
  }
}

// transposed store computed(m,n) -> dst[n*stride + m]
template<int RT, int CT>
__device__ __forceinline__ void emit_t(const float4v* acc, ushort_t* dst, int stride,
                                       int row0, int col0, int gma, int q){
  #pragma unroll
  for (int R = 0; R < RT; R++)
    #pragma unroll
    for (int C = 0; C < CT; C++){
      int c = col0 + 16*C + gma, r0 = row0 + 16*R + 4*q;
      uint2 o;
      o.x = f2bfpk(acc[R*CT+C][0], acc[R*CT+C][1]);
      o.y = f2bfpk(acc[R*CT+C][2], acc[R*CT+C][3]);
      *(uint2*)&dst[(size_t)c*stride + r0] = o;
    }
}
template<int RT, int CT>
__device__ __forceinline__ void emit_split_t(const float4v* acc, ushort_t* dh, ushort_t* dl, int stride,
                                             int row0, int col0, int gma, int q){
  #pragma unroll
  for (int R = 0; R < RT; R++)
    #pragma unroll
    for (int C = 0; C < CT; C++){
      int c = col0 + 16*C + gma, r0 = row0 + 16*R + 4*q;
      ushort4 hh, ll;
      split2(acc[R*CT+C][0], hh.x, ll.x); split2(acc[R*CT+C][1], hh.y, ll.y);
      split2(acc[R*CT+C][2], hh.z, ll.z); split2(acc[R*CT+C][3], hh.w, ll.w);
      *(ushort4*)&dh[(size_t)c*stride + r0] = hh;
      *(ushort4*)&dl[(size_t)c*stride + r0] = ll;
    }
}
template<int NT>
__device__ __forceinline__ void lds_load_mat(ushort_t* dst, const ushort_t* src, int tid){
  for (int i = tid*4; i < 16384; i += NT*4){
    int r = i >> 7, k = i & 127;
    *(ushort4*)&dst[r*SP + k] = *(const ushort4*)&src[i];
  }
}
template<int NT>
__device__ __forceinline__ void lds_store_mat(ushort_t* dst, const ushort_t* src, int tid){
  for (int i = tid*4; i < 16384; i += NT*4){
    int r = i >> 7, k = i & 127;
    *(ushort4*)&dst[i] = *(const ushort4*)&src[r*SP + k];
  }
}

// ---- small: prepU | normv | initG ----
__global__ void k_small(const float* Ux, const float* Uh, const float* kr, const float* ki,
                        ushort_t* UxTh, ushort_t* UxTl, float* Vr, float* Vi,
                        ushort_t* PpH, ushort_t* PpL, ushort_t* PTh, ushort_t* PTl){
  int blk = blockIdx.x, d = threadIdx.x;
  if (blk < 128){
    int i = blk;
    float v = Ux[i*DD + d];
    ushort_t h, l; split2(v, h, l);
    UxTh[d*DD + i] = h; UxTl[d*DD + i] = l;
  } else if (blk < 256){
    __shared__ float red[DD];
    int k = blk - 128;
    float r = kr[k*DD+d], im = ki[k*DD+d];
    red[d] = r*r + im*im;
    __syncthreads();
    for (int s = 64; s > 0; s >>= 1){ if (d < s) red[d] += red[d+s]; __syncthreads(); }
    float nrm = fmaxf(sqrtf(red[0]), 1e-12f);
    Vr[k*DD+d] = r/nrm; Vi[k*DD+d] = im/nrm;
  } else {
    int i = blk - 256;
    float v = Uh[i*DD + d];
    ushort_t h, l; split2(v, h, l);
    PpH[i*DD + d] = h;  PpL[i*DD + d] = l;
    PTh[d*DD + i] = h;  PTl[d*DD + i] = l;
  }
}

// ---- pow2step ----
__global__ __launch_bounds__(512,1) void k_pow2step(ushort_t* PpH, ushort_t* PpL,
                                                    ushort_t* PTh, ushort_t* PTl, int s){
  __shared__ ushort_t Ah[128*SP], Al[128*SP], Bh[128*SP], Bl[128*SP];
  int which = blockIdx.x;
  size_t src = (size_t)(s-1)*16384, dst = (size_t)s*16384;
  int tid = threadIdx.x;
  int w = tid >> 6, lane = tid & 63, gma = lane & 15, q = lane >> 4;
  int row0 = 32*(w >> 1), col0 = 64*(w & 1);
  if (which == 0){
    lds_load_mat<512>(Ah, PTh + src, tid); lds_load_mat<512>(Al, PTl + src, tid);
    lds_load_mat<512>(Bh, PpH + src, tid); lds_load_mat<512>(Bl, PpL + src, tid);
  } else {
    lds_load_mat<512>(Ah, PpH + src, tid); lds_load_mat<512>(Al, PpL + src, tid);
    lds_load_mat<512>(Bh, PTh + src, tid); lds_load_mat<512>(Bl, PTl + src, tid);
  }
  __syncthreads();
  float4v acc[8];
  #pragma unroll
  for (int i = 0; i < 8; i++) acc[i] = (float4v){0.f,0.f,0.f,0.f};
  gemm_t<2,4,true,true>(Ah, Al, Bh, Bl, acc, row0, col0, gma, q);
  if (which == 0) emit_split_t<2,4>(acc, PpH + dst, PpL + dst, 128, row0, col0, gma, q);
  else            emit_split_t<2,4>(acc, PTh + dst, PTl + dst, 128, row0, col0, gma, q);
}

// ---- gchain ----
__global__ __launch_bounds__(512,1) void k_gchain(const ushort_t* PpH, const ushort_t* PpL,
                                                  const ushort_t* PTh, const ushort_t* PTl,
                                                  ushort_t* GTh, ushort_t* GTl){
  __shared__ ushort_t Ah[128*SP], Al[128*SP], Bh[128*SP], Bl[128*SP];
  int t = blockIdx.x;
  int tid = threadIdx.x;
  int w = tid >> 6, lane = tid & 63, gma = lane & 15, q = lane >> 4;
  int row0 = 32*(w >> 1), col0 = 64*(w & 1);
  size_t gslot = (size_t)t * 16384;
  if (t == 0){
    for (int i = tid*4; i < 16384; i += 2048){
      int r = i >> 7, k = i & 127;
      ushort4 zz; zz.x = zz.y = zz.z = zz.w = 0;
      *(ushort4*)&GTl[gslot + i] = zz;
      ushort4 oh;
      oh.x = (r == (k+0)) ? (ushort_t)0x3F80 : (ushort_t)0;
      oh.y = (r == (k+1)) ? (ushort_t)0x3F80 : (ushort_t)0;
      oh.z = (r == (k+2)) ? (ushort_t)0x3F80 : (ushort_t)0;
      oh.w = (r == (k+3)) ? (ushort_t)0x3F80 : (ushort_t)0;
      *(ushort4*)&GTh[gslot + i] = oh;
    }
    return;
  }
  int b0 = __ffs(t) - 1;
  int rem = t & ~(1 << b0);
  if (rem == 0){
    size_t ps = (size_t)b0 * 16384;
    for (int i = tid*4; i < 16384; i += 2048){
      *(ushort4*)&GTh[gslot + i] = *(const ushort4*)&PTh[ps + i];
      *(ushort4*)&GTl[gslot + i] = *(const ushort4*)&PTl[ps + i];
    }
    return;
  }
  lds_load_mat<512>(Ah, PpH + (size_t)b0*16384, tid);
  lds_load_mat<512>(Al, PpL + (size_t)b0*16384, tid);
  while (rem){
    int k = __ffs(rem) - 1;
    rem &= ~(1 << k);
    lds_load_mat<512>(Bh, PTh + (size_t)k*16384, tid);
    lds_load_mat<512>(Bl, PTl + (size_t)k*16384, tid);
    __syncthreads();
    float4v acc[8];
    #pragma unroll
    for (int i = 0; i < 8; i++) acc[i] = (float4v){0.f,0.f,0.f,0.f};
    if (rem){
      gemm_t<2,4,true,true>(Bh, Bl, Ah, Al, acc, row0, col0, gma, q);
      __syncthreads();
      emit_split_t<2,4>(acc, Ah, Al, SP, row0, col0, gma, q);
      __syncthreads();
    } else {
      gemm_t<2,4,true,true>(Ah, Al, Bh, Bl, acc, row0, col0, gma, q);
      emit_split_t<2,4>(acc, GTh + gslot, GTl + gslot, 128, row0, col0, gma, q);
    }
  }
}

// ---- precompMW ----
__global__ __launch_bounds__(256,1) void k_precompMW(const ushort_t* GTh, const ushort_t* GTl,
                                                     const ushort_t* UxTh, const ushort_t* UxTl,
                                                     const float* Vr, const float* Vi,
                                                     ushort_t* Mh, ushort_t* Wh){
  __shared__ ushort_t Bh[128*SP], Bl[128*SP], Ah[128*SP], Al[128*SP];
  int blk = blockIdx.x;
  int tid = threadIdx.x;
  int w = tid >> 6, lane = tid & 63, gma = lane & 15, q = lane >> 4;
  int row0 = 64*(w >> 1), col0 = 64*(w & 1);
  if (blk < 60){
    int t = blk;
    lds_load_mat<256>(Bh, GTh + (size_t)t*16384, tid);
    lds_load_mat<256>(Bl, GTl + (size_t)t*16384, tid);
    lds_load_mat<256>(Ah, UxTh, tid);
    lds_load_mat<256>(Al, UxTl, tid);
    __syncthreads();
    float4v acc[16];
    #pragma unroll
    for (int i = 0; i < 16; i++) acc[i] = (float4v){0.f,0.f,0.f,0.f};
    gemm_t<4,4,true,true>(Ah, Al, Bh, Bl, acc, row0, col0, gma, q);
    __syncthreads();
    emit_split_t<4,4>(acc, Ah, Al, SP, row0, col0, gma, q);
    __syncthreads();
    #pragma unroll
    for (int i = 0; i < 16; i++) acc[i] = (float4v){0.f,0.f,0.f,0.f};
    gemm_t<4,4,true,true>(Bh, Bl, Ah, Al, acc, row0, col0, gma, q);
    #pragma unroll
    for (int R = 0; R < 4; R++)
      #pragma unroll
      for (int C = 0; C < 4; C++){
        int c = col0 + 16*C + gma, r0 = row0 + 16*R + 4*q;
        uint2 o;
        o.x = f2bfpk(acc[R*4+C][0], acc[R*4+C][1]);
        o.y = f2bfpk(acc[R*4+C][2], acc[R*4+C][3]);
        *(uint2*)&Mh[(size_t)t*16384 + c*128 + r0] = o;
      }
  } else {
    int bx = blk - 60;
    int t = bx >> 1, which = bx & 1;
    lds_load_mat<256>(Ah, GTh + (size_t)t*16384, tid);
    lds_load_mat<256>(Al, GTl + (size_t)t*16384, tid);
    const float* V = which ? Vi : Vr;
    for (int i = tid; i < 16384; i += 256){
      int r = i >> 7, k = i & 127;
      ushort_t h, l; split2(V[i], h, l);
      Bh[r*SP + k] = h; Bl[r*SP + k] = l;
    }
    __syncthreads();
    float4v acc[16];
    #pragma unroll
    for (int i = 0; i < 16; i++) acc[i] = (float4v){0.f,0.f,0.f,0.f};
    gemm_t<4,4,true,true>(Ah, Al, Bh, Bl, acc, row0, col0, gma, q);
    #pragma unroll
    for (int R = 0; R < 4; R++)
      #pragma unroll
      for (int C = 0; C < 4; C++){
        int c = col0 + 16*C + gma, r0 = row0 + 16*R + 4*q;
        uint2 o;
        o.x = f2bfpk(acc[R*4+C][0], acc[R*4+C][1]);
        o.y = f2bfpk(acc[R*4+C][2], acc[R*4+C][3]);
        *(uint2*)&Wh[(size_t)bx*16384 + c*128 + r0] = o;
      }
  }
}

// ---- prep (fused qtrans) ----
__global__ __launch_bounds__(128) void k_prep(
    const float* x0, const float* x1, const float* x2, const float* smask,
    const float* Wp0, const float* bp0, const float* Wp1, const float* bp1,
    const float* Wp2, const float* bp2, const float* freq, const float* phem,
    const float* Ux, float* Q, float* Wgt)
{
  __shared__ float xs[768+74+35];
  __shared__ float red[DD];
  __shared__ float nrm3[3];
  __shared__ float ps[6][DD];
  int bt = blockIdx.x; int t = bt % DT;
  int d = threadIdx.x;
  const float* r0 = x0 + (size_t)bt*768;
  for (int k = d; k < 768; k += DD) xs[k] = r0[k];
  const float* r1 = x1 + (size_t)bt*74;
  if (d < 74) xs[768+d] = r1[d];
  const float* r2 = x2 + (size_t)bt*35;
  if (d < 35) xs[768+74+d] = r2[d];
  __syncthreads();
  float rep[3];
  { float acc = bp0[d]; for (int k = 0; k < 768; k++) acc += xs[k]*Wp0[k*DD+d]; rep[0] = fmaxf(acc, 0.f); }
  { float acc = bp1[d]; for (int k = 0; k < 74; k++) acc += xs[768+k]*Wp1[k*DD+d]; rep[1] = fmaxf(acc, 0.f); }
  { float acc = bp2[d]; for (int k = 0; k < 35; k++) acc += xs[768+74+k]*Wp2[k*DD+d]; rep[2] = fmaxf(acc, 0.f); }
  for (int m = 0; m < 3; m++){
    red[d] = rep[m]*rep[m];
    __syncthreads();
    for (int s = 64; s > 0; s >>= 1){ if (d < s) red[d] += red[d+s]; __syncthreads(); }
    if (d == 0) nrm3[m] = sqrtf(red[0]);
    __syncthreads();
  }
  float n0 = nrm3[0], n1 = nrm3[1], n2 = nrm3[2];
  float mx = fmaxf(n0, fmaxf(n1, n2));
  float e0 = expf(n0-mx), e1 = expf(n1-mx), e2 = expf(n2-mx);
  float einv = 1.f/(e0+e1+e2);
  if (d < 3) Wgt[bt*3+d] = (d==0?e0:(d==1?e1:e2))*einv;
  float s0 = smask[bt*2], s1 = smask[bt*2+1];
  int id = (s1 > s0) ? 1 : 0;
  float ph = (float)t * freq[id*DD+d] + phem[id*DD+d];
  float cp = cosf(ph), sp = sinf(ph);
  for (int m = 0; m < 3; m++){
    float a = rep[m] / fmaxf(nrm3[m], 1e-12f);
    ps[m][d]   = a*cp;
    ps[3+m][d] = a*sp;
  }
  __syncthreads();
  float qv[6] = {0.f,0.f,0.f,0.f,0.f,0.f};
  const float* uxr = Ux + (size_t)d*DD;
  for (int p = 0; p < DD; p++){
    float u = uxr[p];
    #pragma unroll
    for (int j = 0; j < 6; j++) qv[j] += u * ps[j][p];
  }
  #pragma unroll
  for (int j = 0; j < 6; j++)
    Q[((size_t)(j*BT) + bt)*DD + d] = qv[j];
}

// ---- vtrans: per t, A'[j,b] = G_t^T q_{j,b} for all 192 vectors ----
// A = GT rows (M=128), B = q vectors (N=192, staged bf16 k-major).
// D[m][n] = (G^T q_n)[m]; emit_t -> At[t][n][m] = [vector][component], vector stores.
__global__ __launch_bounds__(512,1) void k_vtrans(const ushort_t* GTh, const float* Q, ushort_t* At){
  __shared__ ushort_t Ah[128*SP];
  __shared__ ushort_t Bs[192*SP];
  int t = blockIdx.x;
  int tid = threadIdx.x;
  int w = tid >> 6, lane = tid & 63, gma = lane & 15, q = lane >> 4;
  int row0 = (w & 3)*32, col0 = (w >> 2)*96;
  lds_load_mat<512>(Ah, GTh + (size_t)t*16384, tid);
  for (int i = tid*4; i < 192*128; i += 2048){
    int m = i >> 7, k = i & 127;
    int j = m >> 5, b = m & 31;
    const float* src = &Q[((size_t)(j*BT) + b*DT + t)*DD + k];
    uint2 o; o.x = f2bfpk(src[0], src[1]); o.y = f2bfpk(src[2], src[3]);
    *(uint2*)&Bs[m*SP + k] = o;
  }
  __syncthreads();
  float4v acc[12];
  #pragma unroll
  for (int i = 0; i < 12; i++) acc[i] = (float4v){0.f,0.f,0.f,0.f};
  gemm_t<2,6,false,false>(Ah, Ah, Bs, Bs, acc, row0, col0, gma, q);
  emit_t<2,6>(acc, At + (size_t)t*24576, 128, row0, col0, gma, q);
}

// ---- zbuild: fused rank-6 Y build + lambda-prefix; writes Z into S ----
// Y_t[r][c] = sum_j combo_j[r]*raw_j[c], combos from A' with per-(b,t) weights.
__global__ __launch_bounds__(256) void k_zbuild(ushort_t* S, const ushort_t* At,
                                                const float* Wgt, const float* lamp){
  __shared__ ushort_t As[6*DD];
  __shared__ float wl[3];
  int blk = blockIdx.x;            // 512 = 32 b x 16 slabs
  int b = blk >> 4, slab = blk & 15;
  int tid = threadIdx.x;
  int r = slab*8 + (tid >> 5);
  int c0 = (tid & 31)*4;
  float lam = lamp[0];
  float z0=0.f, z1=0.f, z2=0.f, z3=0.f;
  size_t off = (size_t)slab*1024 + tid*4;
  for (int t = 0; t < DT; t++){
    __syncthreads();
    if (tid < 192){
      int i = tid*4;
      int jj = i >> 7, n = i & 127;
      *(ushort4*)&As[i] = *(const ushort4*)&At[(size_t)t*24576 + (jj*32 + b)*128 + n];
    }
    if (tid < 3) wl[tid] = Wgt[(b*DT + t)*3 + tid];
    __syncthreads();
    float ar[6];
    #pragma unroll
    for (int jj = 0; jj < 6; jj++) ar[jj] = bf2f(As[jj*128 + r]);
    float cb[6];
    cb[0] = wl[0]*(ar[0]+ar[3]); cb[1] = wl[1]*(ar[1]+ar[4]); cb[2] = wl[2]*(ar[2]+ar[5]);
    cb[3] = wl[0]*(ar[3]-ar[0]); cb[4] = wl[1]*(ar[4]-ar[1]); cb[5] = wl[2]*(ar[5]-ar[2]);
    float y0=0.f, y1=0.f, y2=0.f, y3=0.f;
    #pragma unroll
    for (int jj = 0; jj < 6; jj++){
      ushort4 a4 = *(const ushort4*)&As[jj*128 + c0];
      float w_ = cb[jj];
      y0 += w_*bf2f(a4.x); y1 += w_*bf2f(a4.y);
      y2 += w_*bf2f(a4.z); y3 += w_*bf2f(a4.w);
    }
    z0 = lam*z0 + y0; z1 = lam*z1 + y1;
    z2 = lam*z2 + y2; z3 = lam*z3 + y3;
    uint2 o; o.x = f2bfpk(z0, z1); o.y = f2bfpk(z2, z3);
    *(uint2*)&S[((size_t)(t*32 + b))*16384 + off] = o;
  }
}

// ---- conjmid (512 thr, per (t,b)): S <- (1-l) M S M^T + c_t I ----
__global__ __launch_bounds__(512,4) void k_conjmid(ushort_t* S, const ushort_t* Mh,
                                                   const float* lamp){
  __shared__ ushort_t Bh[128*SP], Zs[128*SP];
  int blk = blockIdx.x;
  int t = blk >> 5;
  size_t slot = (size_t)blk * 16384;
  int tid = threadIdx.x;
  int w = tid >> 6, lane = tid & 63, gma = lane & 15, q = lane >> 4;
  int row0 = 32*(w >> 1), col0 = 64*(w & 1);
  lds_load_mat<512>(Bh, Mh + (size_t)t*16384, tid);
  lds_load_mat<512>(Zs, S + slot, tid);
  __syncthreads();
  float lam = lamp[0];
  float oml = 1.f - lam;
  float ct = powf(lam, (float)(t+1)) / 128.f;
  float4v acc[8];
  #pragma unroll
  for (int i = 0; i < 8; i++) acc[i] = (float4v){0.f,0.f,0.f,0.f};
  gemm_t<2,4,false,false>(Zs, Zs, Bh, Bh, acc, row0, col0, gma, q);
  __syncthreads();
  emit_t<2,4>(acc, Zs, SP, row0, col0, gma, q);
  __syncthreads();
  #pragma unroll
  for (int i = 0; i < 8; i++) acc[i] = (float4v){0.f,0.f,0.f,0.f};
  gemm_t<2,4,false,false>(Zs, Zs, Bh, Bh, acc, row0, col0, gma, q);
  __syncthreads();
  #pragma unroll
  for (int R = 0; R < 2; R++)
    #pragma unroll
    for (int C = 0; C < 4; C++){
      int c = col0 + 16*C + gma, r0 = row0 + 16*R + 4*q;
      float v0 = oml*acc[R*4+C][0] + ((c == r0+0) ? ct : 0.f);
      float v1 = oml*acc[R*4+C][1] + ((c == r0+1) ? ct : 0.f);
      float v2 = oml*acc[R*4+C][2] + ((c == r0+2) ? ct : 0.f);
      float v3 = oml*acc[R*4+C][3] + ((c == r0+3) ? ct : 0.f);
      uint2 o; o.x = f2bfpk(v0, v1); o.y = f2bfpk(v2, v3);
      *(uint2*)&Zs[(size_t)c*SP + r0] = o;
    }
  __syncthreads();
  lds_store_mat<512>(S + slot, Zs, tid);
}

// ---- prefix: Z_t = lam*Z_{t-1} + Y_t (32 chains) ----
__global__ __launch_bounds__(256) void k_prefix(ushort_t* S, const float* lamp){
  int blk = blockIdx.x;            // 512 = 32 chains x 16 slabs
  int chain = blk >> 4, slab = blk & 15;
  int tid = threadIdx.x;
  size_t off = (size_t)slab*1024 + tid*4;
  float lam = lamp[0];
  float a0=0.f, a1=0.f, a2=0.f, a3=0.f;
  size_t addr = (size_t)chain*16384 + off;
  const size_t step = (size_t)32*16384;
  ushort4 nxt = *(const ushort4*)&S[addr];
  for (int t = 0; t < DT; t++){
    ushort4 u = nxt;
    if (t < DT-1) nxt = *(const ushort4*)&S[addr + step];
    a0 = lam*a0 + bf2f(u.x); a1 = lam*a1 + bf2f(u.y);
    a2 = lam*a2 + bf2f(u.z); a3 = lam*a3 + bf2f(u.w);
    uint2 o; o.x = f2bfpk(a0, a1); o.y = f2bfpk(a2, a3);
    *(uint2*)&S[addr] = o;
    addr += step;
  }
}

// ---- meas (512 thr, per (tb,h)): stage1 Vs*C^T then 16 diag tiles ----
__global__ __launch_bounds__(512,2) void k_meas(const ushort_t* S, const ushort_t* Wh,
                                                const float* lamp, float* Probs){
  __shared__ ushort_t Vs[128*SP], Ss[128*SP];
  __shared__ float Pd[64];
  int blk = blockIdx.x;
  int tb = blk >> 1, h = blk & 1;
  int t = tb >> 5;
  int tid = threadIdx.x;
  int w = tid >> 6, lane = tid & 63, gma = lane & 15, q = lane >> 4;
  int row0 = 32*(w >> 1), col0 = 64*(w & 1);
  size_t slot = (size_t)tb * 16384;
  size_t wbase = (size_t)(t*2) * 16384;
  for (int i = tid*4; i < 16384; i += 2048){
    int r = i >> 7, k = i & 127;
    size_t gsrc = wbase + ((r < 64) ? 0 : 16384) + (size_t)(64*h + (r & 63))*128 + k;
    *(ushort4*)&Vs[r*SP+k] = *(const ushort4*)&Wh[gsrc];
    *(ushort4*)&Ss[r*SP+k] = *(const ushort4*)&S[slot + i];
  }
  if (tid < 64) Pd[tid] = 0.f;
  __syncthreads();
  {
    float4v acc[8];
    #pragma unroll
    for (int i = 0; i < 8; i++) acc[i] = (float4v){0.f,0.f,0.f,0.f};
    gemm_t<2,4,false,false>(Ss, Ss, Vs, Vs, acc, row0, col0, gma, q);
    __syncthreads();
    emit_t<2,4>(acc, Ss, SP, row0, col0, gma, q);            // Ss = Vs * C^T
  }
  __syncthreads();
  #pragma unroll
  for (int g = 0; g < 2; g++){
    int ti = 2*w + g;
    int grp = ti >> 2, sub = ti & 3;
    int arow = (((grp == 1) || (grp == 2)) ? 64 : 0) + 16*sub + gma;
    int brow = (((grp == 1) || (grp == 3)) ? 64 : 0) + 16*sub + gma;
    float coef = (grp == 2) ? -1.f : 1.f;
    float4v a1 = (float4v){0.f,0.f,0.f,0.f};
    #pragma unroll
    for (int ks = 0; ks < 4; ks++){
      int ko = ks*32 + q*8;
      bf16x8 aF = *(const bf16x8*)&Ss[arow*SP + ko];
      bf16x8 bF = *(const bf16x8*)&Vs[brow*SP + ko];
      a1 = __builtin_amdgcn_mfma_f32_16x16x32_bf16(aF, bF, a1, 0, 0, 0);
    }
    if ((gma >> 2) == q) atomicAdd(&Pd[16*sub + gma], coef * a1[gma & 3]);
  }
  __syncthreads();
  if (tid < 64){
    float lam = lamp[0];
    float ct = powf(lam, (float)(t+1)) / 128.f;
    Probs[(size_t)tb*DD + 64*h + tid] = (1.f - lam)*Pd[tid] + ct;
  }
}

// ---- head ----
__global__ __launch_bounds__(64) void k_head(const float* Probs, const float* W1, const float* b1,
                        const float* W2, const float* b2, float* out)
{
  __shared__ float ps[DD];
  __shared__ float hid[64];
  __shared__ float ov[4];
  int tb = blockIdx.x;
  int tid = threadIdx.x;
  ps[tid] = Probs[(size_t)tb*DD + tid];
  ps[tid+64] = Probs[(size_t)tb*DD + 64 + tid];
  __syncthreads();
  float acc = b1[tid];
  for (int dd = 0; dd < DD; dd++) acc += ps[dd]*W1[dd*64 + tid];
  hid[tid] = fmaxf(acc, 0.f);
  __syncthreads();
  if (tid < 4){
    float o = b2[tid];
    for (int j = 0; j < 64; j++) o += hid[j]*W2[j*4 + tid];
    ov[tid] = tanhf(o);
  }
  __syncthreads();
  if (tid == 0){
    float m = fmaxf(fmaxf(ov[0],ov[1]), fmaxf(ov[2],ov[3]));
    float lse = logf(expf(ov[0]-m)+expf(ov[1]-m)+expf(ov[2]-m)+expf(ov[3]-m));
    int t = tb >> 5, b = tb & 31;
    float* o = out + ((size_t)(b*DT + t))*4;
    o[0] = ov[0]-m-lse; o[1] = ov[1]-m-lse;
    o[2] = ov[2]-m-lse; o[3] = ov[3]-m-lse;
  }
}

extern "C" void kernel_launch(void* const* d_in, const int* in_sizes, int n_in,
                              void* d_out, int out_size, void* d_ws, size_t ws_size,
                              hipStream_t stream)
{
  const float* x0    = (const float*)d_in[0];
  const float* x1    = (const float*)d_in[1];
  const float* x2    = (const float*)d_in[2];
  const float* smask = (const float*)d_in[3];
  const float* Wp0   = (const float*)d_in[4];
  const float* bp0   = (const float*)d_in[5];
  const float* Wp1   = (const float*)d_in[6];
  const float* bp1   = (const float*)d_in[7];
  const float* Wp2   = (const float*)d_in[8];
  const float* bp2   = (const float*)d_in[9];
  const float* freq  = (const float*)d_in[10];
  const float* phem  = (const float*)d_in[11];
  const float* Ux    = (const float*)d_in[12];
  const float* Uh    = (const float*)d_in[13];
  const float* lamp  = (const float*)d_in[14];
  const float* kr    = (const float*)d_in[15];
  const float* ki    = (const float*)d_in[16];
  const float* W1    = (const float*)d_in[17];
  const float* b1    = (const float*)d_in[18];
  const float* W2    = (const float*)d_in[19];
  const float* b2    = (const float*)d_in[20];

  char* ws = (char*)d_ws;
  auto alignup = [](size_t x){ return (x + 255) & ~(size_t)255; };
  size_t off = 0;
  ushort_t* S   = (ushort_t*)(ws + off); off = alignup(off + (size_t)1920*16384*sizeof(ushort_t));
  float* Qbuf   = (float*)(ws + off);    off = alignup(off + (size_t)6*BT*DD*sizeof(float));
  float* Wgt    = (float*)(ws + off);    off = alignup(off + (size_t)BT*3*sizeof(float));
  float* Vr     = (float*)(ws + off);    off = alignup(off + (size_t)DD*DD*sizeof(float));
  float* Vi     = (float*)(ws + off);    off = alignup(off + (size_t)DD*DD*sizeof(float));
  ushort_t* UxTh = (ushort_t*)(ws + off); off = alignup(off + (size_t)DD*DD*sizeof(ushort_t));
  ushort_t* UxTl = (ushort_t*)(ws + off); off = alignup(off + (size_t)DD*DD*sizeof(ushort_t));
  float* Probs  = (float*)(ws + off);    off = alignup(off + (size_t)BT*DD*sizeof(float));
  ushort_t* PpH = (ushort_t*)(ws + off); off = alignup(off + (size_t)6*16384*sizeof(ushort_t));
  ushort_t* PpL = (ushort_t*)(ws + off); off = alignup(off + (size_t)6*16384*sizeof(ushort_t));
  ushort_t* PTh = (ushort_t*)(ws + off); off = alignup(off + (size_t)6*16384*sizeof(ushort_t));
  ushort_t* PTl = (ushort_t*)(ws + off); off = alignup(off + (size_t)6*16384*sizeof(ushort_t));
  ushort_t* Mh  = (ushort_t*)(ws + off); off = alignup(off + (size_t)60*16384*sizeof(ushort_t));
  ushort_t* Wmh = (ushort_t*)(ws + off); off = alignup(off + (size_t)120*16384*sizeof(ushort_t));
  ushort_t* GTh = (ushort_t*)(ws + off); off = alignup(off + (size_t)60*16384*sizeof(ushort_t));
  ushort_t* GTl = (ushort_t*)(ws + off); off = alignup(off + (size_t)60*16384*sizeof(ushort_t));
  ushort_t* At  = (ushort_t*)(ws + off); off = alignup(off + (size_t)60*24576*sizeof(ushort_t));
  (void)ws_size; (void)in_sizes; (void)n_in; (void)out_size;

  k_small<<<384, 128, 0, stream>>>(Ux, Uh, kr, ki, UxTh, UxTl, Vr, Vi, PpH, PpL, PTh, PTl);
  k_prep<<<BT, 128, 0, stream>>>(x0, x1, x2, smask, Wp0, bp0, Wp1, bp1, Wp2, bp2, freq, phem, Ux, Qbuf, Wgt);
  for (int s = 1; s <= 5; s++)
    k_pow2step<<<2, 512, 0, stream>>>(PpH, PpL, PTh, PTl, s);
  k_gchain<<<60, 512, 0, stream>>>(PpH, PpL, PTh, PTl, GTh, GTl);
  k_precompMW<<<180, 256, 0, stream>>>(GTh, GTl, UxTh, UxTl, Vr, Vi, Mh, Wmh);
  k_vtrans<<<60, 512, 0, stream>>>(GTh, Qbuf, At);
  k_zbuild<<<512, 256, 0, stream>>>(S, At, Wgt, lamp);
  k_conjmid<<<1920, 512, 0, stream>>>(S, Mh, lamp);
  k_prefix<<<512, 256, 0, stream>>>(S, lamp);
  k_meas<<<3840, 512, 0, stream>>>(S, Wmh, lamp, Probs);
  k_head<<<BT, 64, 0, stream>>>(Probs, W1, b1, W2, b2, (float*)d_out);
}